// Round 7
// baseline (132.580 us; speedup 1.0000x reference)
//
#include <hip/hip_runtime.h>

#define NSLOTS 131072
#define NMASK  (NSLOTS-1)
#define NBATCH 256
#define DMEM   64
#define DIN    256
#define DCOMB  71
#define SPB    64                 // slots per fallback-stats tile
#define NBLK   (NSLOTS/SPB)       // 2048
#define EPSF   1e-8f

typedef unsigned int   u32;
typedef unsigned short u16;
typedef __bf16 bf16x8 __attribute__((ext_vector_type(8)));
typedef float  f32x4  __attribute__((ext_vector_type(4)));

__device__ __forceinline__ u16 f2bf(float f) {
  u32 u = __builtin_bit_cast(u32, f);
  u += 0x7fffu + ((u >> 16) & 1u);          // RNE
  return (u16)(u >> 16);
}
__device__ __forceinline__ float bf2f(u16 v) {
  return __builtin_bit_cast(float, ((u32)v) << 16);
}
__device__ __forceinline__ u32 pk2(float a, float b) {
  return (u32)f2bf(a) | ((u32)f2bf(b) << 16);
}
__device__ __forceinline__ float blo(u32 u){ return __builtin_bit_cast(float, u << 16); }
__device__ __forceinline__ float bhi(u32 u){ return __builtin_bit_cast(float, u & 0xffff0000u); }

// ---------------- kernel 1: combined GEMM + per-batch params ----------------
// params[b*8]: {abk = ks/kn, C = |ks|, gate, ck0, ck1, ck2, -, -}
__global__ __launch_bounds__(128) void ntm_prep(
    const float* __restrict__ inp, const float* __restrict__ W,
    const float* __restrict__ bias, u16* __restrict__ keysbf,
    float* __restrict__ params)
{
  __shared__ float comb[DCOMB];
  const int b = blockIdx.x;
  const int t = threadIdx.x;
  if (t < DCOMB) {
    float acc = bias[t];
    const float* ip = inp + (size_t)b * DIN;
    for (int i = 0; i < DIN; ++i) acc = fmaf(ip[i], W[i*DCOMB + t], acc);
    comb[t] = acc;
  }
  __syncthreads();
  if (t < 64) {
    float k = comb[t];
    keysbf[b*64 + t] = f2bf(k);
    float sq = k * k;
#pragma unroll
    for (int d = 1; d < 64; d <<= 1) sq += __shfl_xor(sq, d, 64);
    if (t == 0) {
      float kn = sqrtf(sq);
      float ks = comb[64];
      params[b*8+0] = ks / kn;                         // abk
      params[b*8+1] = fabsf(ks);                       // softmax shift C (>= max logit)
      params[b*8+2] = 1.f/(1.f + __expf(-comb[65]));   // gate
      float c0 = comb[66], c1 = comb[67], c2 = comb[68];
      float mx = fmaxf(c0, fmaxf(c1, c2));
      float e0 = __expf(c0-mx), e1 = __expf(c1-mx), e2 = __expf(c2-mx);
      float inv = 1.f/(e0+e1+e2);
      params[b*8+3] = e0*inv; params[b*8+4] = e1*inv; params[b*8+5] = e2*inv;
    }
  }
}

// ---------------- kernel A: dots -> u = exp(l - C) (bf16, coalesced) + partial sums ----------------
// tile: 256 slots x 64 batches. grid (4 batch-quarters FAST, 512 slot tiles).
// Register-prefetch double-buffered staging hides HBM latency under compute.
__global__ __launch_bounds__(512, 6) void ntm_dots(
    const u16* __restrict__ keysbf, const float* __restrict__ memory,
    const float* __restrict__ params, u16* __restrict__ ug,
    float* __restrict__ sumpart)
{
  __shared__ __align__(16) u16 pool[64*256];        // 32 KB: u bf16, swizzled 8B chunks
  __shared__ __align__(16) u16 meml[2][64*DMEM];    // 2 x 8 KB subtile, swizzled
  __shared__ float invmn[2][64];
  const int t     = threadIdx.x;
  const int bbase = blockIdx.x * 64;     // batch quarter (fast axis -> L2/L3 sharing)
  const int s0    = blockIdx.y * 256;    // slot tile

  const int w   = t >> 6, L = t & 63;
  const int li  = L & 15, hi4 = L >> 4;
  const int bt  = w & 3;            // batch tile (16 batches)
  const int sh  = w >> 2;           // slot half of subtile (32 slots)
  const int bb  = bbase + bt*16 + li;
  const int prow = bt*16 + li;      // pool row 0..63
  const uint4* kb = (const uint4*)(keysbf + (size_t)bb * DMEM);
  const float abk = params[bb*8+0];
  const float C   = params[bb*8+1];
  float s_acc = 0.f;

  const int r  = t >> 3, c8 = t & 7;
  const float* mprow = memory + (size_t)(s0 + r) * DMEM + c8 * 8;
  float4 pf0 = *(const float4*)(mprow);
  float4 pf1 = *(const float4*)(mprow + 4);

  for (int st = 0; st < 4; ++st) {
    const int cur = st & 1;
    { // stage prefetched subtile regs -> LDS; issue next prefetch before barrier
      uint4 v;
      v.x = pk2(pf0.x, pf0.y); v.y = pk2(pf0.z, pf0.w);
      v.z = pk2(pf1.x, pf1.y); v.w = pk2(pf1.z, pf1.w);
      *(uint4*)&meml[cur][r*DMEM + ((c8 ^ (r & 7)) << 3)] = v;
      float sq = pf0.x*pf0.x + pf0.y*pf0.y + pf0.z*pf0.z + pf0.w*pf0.w
               + pf1.x*pf1.x + pf1.y*pf1.y + pf1.z*pf1.z + pf1.w*pf1.w;
      sq += __shfl_xor(sq, 1, 64);
      sq += __shfl_xor(sq, 2, 64);
      sq += __shfl_xor(sq, 4, 64);
      if (c8 == 0) invmn[cur][r] = rsqrtf(sq);
      if (st < 3) {
        const float* mp = memory + (size_t)(s0 + (st+1)*64 + r) * DMEM + c8 * 8;
        pf0 = *(const float4*)mp;
        pf1 = *(const float4*)(mp + 4);
      }
    }
    __syncthreads();

    f32x4 zero = {0.f, 0.f, 0.f, 0.f};
    f32x4 acc[2] = {zero, zero};
#pragma unroll
    for (int ks = 0; ks < 2; ++ks) {
      int cb = ks*4 + hi4;
      bf16x8 bfr = __builtin_bit_cast(bf16x8, kb[cb]);
#pragma unroll
      for (int rt = 0; rt < 2; ++rt) {
        int rr = sh*32 + rt*16 + li;
        bf16x8 af = __builtin_bit_cast(bf16x8, *(const uint4*)&meml[cur][rr*DMEM + ((cb ^ (rr&7)) << 3)]);
        acc[rt] = __builtin_amdgcn_mfma_f32_16x16x32_bf16(af, bfr, acc[rt], 0, 0, 0);
      }
    }

    // u -> pool (swizzled 8B chunks within this subtile's 16-chunk group)
#pragma unroll
    for (int rt = 0; rt < 2; ++rt) {
      int sbase = sh*32 + rt*16 + hi4*4;   // slot within subtile
      float wv[4];
#pragma unroll
      for (int rj = 0; rj < 4; ++rj)
        wv[rj] = __expf(acc[rt][rj] * abk * invmn[cur][sbase + rj] - C);
      s_acc += wv[0] + wv[1] + wv[2] + wv[3];
      uint2 pkd;
      pkd.x = pk2(wv[0], wv[1]);
      pkd.y = pk2(wv[2], wv[3]);
      int chunk = st*16 + ((sbase >> 2) ^ (prow & 15));
      *(uint2*)&pool[prow*256 + chunk*4] = pkd;
    }
    __syncthreads();
  }

  // partial sums: reduce over hi4 groups (this wave covers 128 slots for batch bb)
  s_acc += __shfl_xor(s_acc, 16, 64);
  s_acc += __shfl_xor(s_acc, 32, 64);
  if (hi4 == 0) sumpart[(size_t)bb*1024 + blockIdx.y*2 + sh] = s_acc;

  // write u coalesced: 8 threads/row, 64 B each (512 B contiguous per row)
  {
    int row = t >> 3, seg = t & 7;
    uint2 wu[8];
#pragma unroll
    for (int j = 0; j < 8; ++j) {
      int c = seg*8 + j;
      int cs = (c & 48) | ((c ^ row) & 15);
      wu[j] = *(const uint2*)&pool[row*256 + cs*4];
    }
    uint4* dst = (uint4*)(ug + (size_t)(bbase + row) * NSLOTS + s0 + seg*32);
#pragma unroll
    for (int j2 = 0; j2 < 4; ++j2) {
      uint4 v; v.x = wu[j2*2].x; v.y = wu[j2*2].y; v.z = wu[j2*2+1].x; v.w = wu[j2*2+1].y;
      dst[j2] = v;
    }
  }
}

// ---------------- kernel 3: global S per batch ----------------
__global__ __launch_bounds__(256) void ntm_reduce(
    const float* __restrict__ sumpart, float* __restrict__ Sv, int nparts)
{
  __shared__ float red[4];
  const int b = blockIdx.x, t = threadIdx.x;
  const int w = t >> 6, L = t & 63;
  float s = 0.f;
  for (int i = t; i < nparts; i += 256) s += sumpart[(size_t)b*nparts + i];
#pragma unroll
  for (int d = 1; d < 64; d <<= 1) s += __shfl_xor(s, d, 64);
  if (L == 0) red[w] = s;
  __syncthreads();
  if (t == 0) Sv[b] = red[0] + red[1] + red[2] + red[3];
}

// ---------------- kernel B: pure streaming gate-blend + 3-tap circular conv (vectorized) ----------------
// grid (64, 256), 256 threads; block covers one batch row x 2048 slots; 8 slots/thread.
__global__ __launch_bounds__(256, 8) void ntm_conv(
    const u16* __restrict__ ug, const float* __restrict__ params,
    const float* __restrict__ Sv, const float* __restrict__ prev,
    float* __restrict__ out)
{
  const int b    = blockIdx.y;
  const int t    = threadIdx.x;
  const int so   = blockIdx.x * 2048 + t * 8;
  const int L    = t & 63;
  const float gg  = params[b*8+2];
  const float c0f = params[b*8+3], c1f = params[b*8+4], c2f = params[b*8+5];
  const float og  = 1.f - gg;
  const float gs  = gg / Sv[b];
  const float* pv = prev + (size_t)b * NSLOTS;
  const u16*   uv = ug   + (size_t)b * NSLOTS;
  float*       ov = out  + (size_t)b * NSLOTS;

  float4 p0 = *(const float4*)(pv + so);
  float4 p1 = *(const float4*)(pv + so + 4);
  uint4  uu = *(const uint4*)(uv + so);    // 8 bf16
  float f[8];
  f[0] = fmaf(og, p0.x, gs * blo(uu.x));
  f[1] = fmaf(og, p0.y, gs * bhi(uu.x));
  f[2] = fmaf(og, p0.z, gs * blo(uu.y));
  f[3] = fmaf(og, p0.w, gs * bhi(uu.y));
  f[4] = fmaf(og, p1.x, gs * blo(uu.z));
  f[5] = fmaf(og, p1.y, gs * bhi(uu.z));
  f[6] = fmaf(og, p1.z, gs * blo(uu.w));
  f[7] = fmaf(og, p1.w, gs * bhi(uu.w));

  float fl = __shfl_up(f[7], 1, 64);
  float fr = __shfl_down(f[0], 1, 64);
  if (L == 0) {                            // left edge of this wave's 512-slot span
    int sm = (so - 1) & NMASK;
    fl = fmaf(og, pv[sm], gs * bf2f(uv[sm]));
  }
  if (L == 63) {                           // right edge
    int sp = (so + 8) & NMASK;
    fr = fmaf(og, pv[sp], gs * bf2f(uv[sp]));
  }

  float4 o0, o1;
  o0.x = c0f*fl   + c1f*f[0] + c2f*f[1];
  o0.y = c0f*f[0] + c1f*f[1] + c2f*f[2];
  o0.z = c0f*f[1] + c1f*f[2] + c2f*f[3];
  o0.w = c0f*f[2] + c1f*f[3] + c2f*f[4];
  o1.x = c0f*f[3] + c1f*f[4] + c2f*f[5];
  o1.y = c0f*f[4] + c1f*f[5] + c2f*f[6];
  o1.z = c0f*f[5] + c1f*f[6] + c2f*f[7];
  o1.w = c0f*f[6] + c1f*f[7] + c2f*fr;
  *(float4*)(ov + so)     = o0;
  *(float4*)(ov + so + 4) = o1;
}

// ================= fallback path (ws too small): round-3 validated kernels =================
__global__ __launch_bounds__(512, 8) void ntm_stats_fb(
    const u16* __restrict__ keysbf, const float* __restrict__ memory,
    const float* __restrict__ params, float* __restrict__ sumpart)
{
  __shared__ __align__(16) u16 meml[SPB*DMEM];
  __shared__ float invmn[SPB];
  const int t     = threadIdx.x;
  const int s0    = blockIdx.x * SPB;
  const int bbase = blockIdx.y * 128;
  {
    int r = t >> 3, c8 = t & 7;
    const float* mp = memory + (size_t)(s0 + r) * DMEM + c8 * 8;
    float4 f0 = *(const float4*)mp;
    float4 f1 = *(const float4*)(mp + 4);
    uint4 v;
    v.x = pk2(f0.x, f0.y); v.y = pk2(f0.z, f0.w);
    v.z = pk2(f1.x, f1.y); v.w = pk2(f1.z, f1.w);
    *(uint4*)&meml[r*DMEM + ((c8 ^ (r & 7)) << 3)] = v;
    float sq = f0.x*f0.x + f0.y*f0.y + f0.z*f0.z + f0.w*f0.w
             + f1.x*f1.x + f1.y*f1.y + f1.z*f1.z + f1.w*f1.w;
    sq += __shfl_xor(sq, 1, 64);
    sq += __shfl_xor(sq, 2, 64);
    sq += __shfl_xor(sq, 4, 64);
    if (c8 == 0) invmn[r] = rsqrtf(sq);
  }
  __syncthreads();
  const int w = t >> 6, L = t & 63;
  const int li = L & 15, hi4 = L >> 4;
  const int bb = bbase + w*16 + li;
  const uint4* kb = (const uint4*)(keysbf + (size_t)bb * DMEM);
  f32x4 zero = {0.f, 0.f, 0.f, 0.f};
  f32x4 acc[4];
#pragma unroll
  for (int rt = 0; rt < 4; ++rt) acc[rt] = zero;
#pragma unroll
  for (int ks = 0; ks < 2; ++ks) {
    int cb = ks*4 + hi4;
    bf16x8 bfr = __builtin_bit_cast(bf16x8, kb[cb]);
#pragma unroll
    for (int rt = 0; rt < 4; ++rt) {
      int r = rt*16 + li;
      bf16x8 af = __builtin_bit_cast(bf16x8, *(const uint4*)&meml[r*DMEM + ((cb ^ (r&7)) << 3)]);
      acc[rt] = __builtin_amdgcn_mfma_f32_16x16x32_bf16(af, bfr, acc[rt], 0, 0, 0);
    }
  }
  float abk = params[bb*8 + 0];
  float C   = params[bb*8 + 1];
  float s = 0.f;
#pragma unroll
  for (int rt = 0; rt < 4; ++rt)
#pragma unroll
    for (int r = 0; r < 4; ++r) {
      int sl = rt*16 + hi4*4 + r;
      s += __expf(acc[rt][r] * abk * invmn[sl] - C);
    }
  s += __shfl_xor(s, 16, 64);
  s += __shfl_xor(s, 32, 64);
  if (hi4 == 0) sumpart[(size_t)bb*NBLK + blockIdx.x] = s;
}

__global__ __launch_bounds__(512, 8) void ntm_final_fb(
    const u16* __restrict__ keysbf, const float* __restrict__ memory,
    const float* __restrict__ params, const float* __restrict__ Sv,
    const float* __restrict__ prev, float* __restrict__ out)
{
  __shared__ __align__(16) u16 pool[128*DMEM];
  __shared__ __align__(16) u16 meml[SPB*DMEM];
  __shared__ __align__(16) u16 halom[2*DMEM];
  __shared__ float invmn[SPB];
  __shared__ float invhn[2];
  __shared__ u16 hlo[128], hhi[128];
  const int t     = threadIdx.x;
  const int s0    = blockIdx.x * SPB;
  const int bbase = blockIdx.y * 128;
  {
    int r = t >> 3, c8 = t & 7;
    const float* mp = memory + (size_t)(s0 + r) * DMEM + c8 * 8;
    float4 f0 = *(const float4*)mp;
    float4 f1 = *(const float4*)(mp + 4);
    uint4 v;
    v.x = pk2(f0.x, f0.y); v.y = pk2(f0.z, f0.w);
    v.z = pk2(f1.x, f1.y); v.w = pk2(f1.z, f1.w);
    *(uint4*)&meml[r*DMEM + ((c8 ^ (r & 7)) << 3)] = v;
    float sq = f0.x*f0.x + f0.y*f0.y + f0.z*f0.z + f0.w*f0.w
             + f1.x*f1.x + f1.y*f1.y + f1.z*f1.z + f1.w*f1.w;
    sq += __shfl_xor(sq, 1, 64);
    sq += __shfl_xor(sq, 2, 64);
    sq += __shfl_xor(sq, 4, 64);
    if (c8 == 0) invmn[r] = rsqrtf(sq);
  }
  if (t < 128) {
    int h = t >> 6, m = t & 63;
    int gs = (s0 + (h ? SPB : -1)) & NMASK;
    float v = memory[(size_t)gs * DMEM + m];
    halom[h*DMEM + m] = f2bf(v);
    float sq = v * v;
#pragma unroll
    for (int d = 1; d < 64; d <<= 1) sq += __shfl_xor(sq, d, 64);
    if (m == 0) invhn[h] = rsqrtf(sq);
  }
  __syncthreads();
  const int w = t >> 6, L = t & 63;
  const int li = L & 15, hi4 = L >> 4;
  const int bb = bbase + w*16 + li;
  const int pb = w*16 + li;
  const uint4* kb = (const uint4*)(keysbf + (size_t)bb * DMEM);
  f32x4 zero = {0.f, 0.f, 0.f, 0.f};
  f32x4 acc[4];
#pragma unroll
  for (int rt = 0; rt < 4; ++rt) acc[rt] = zero;
#pragma unroll
  for (int ks = 0; ks < 2; ++ks) {
    int cb = ks*4 + hi4;
    bf16x8 bfr = __builtin_bit_cast(bf16x8, kb[cb]);
#pragma unroll
    for (int rt = 0; rt < 4; ++rt) {
      int r = rt*16 + li;
      bf16x8 af = __builtin_bit_cast(bf16x8, *(const uint4*)&meml[r*DMEM + ((cb ^ (r&7)) << 3)]);
      acc[rt] = __builtin_amdgcn_mfma_f32_16x16x32_bf16(af, bfr, acc[rt], 0, 0, 0);
    }
  }
  if (t < 256) {
    int hb = t & 127, hh = t >> 7;
    int gb = bbase + hb;
    const uint4* kb2 = (const uint4*)(keysbf + (size_t)gb * DMEM);
    float dot = 0.f;
#pragma unroll
    for (int mb = 0; mb < 8; ++mb) {
      uint4 kv = kb2[mb];
      uint4 mv = *(const uint4*)&halom[hh*DMEM + mb*8];
      dot += blo(kv.x)*blo(mv.x) + bhi(kv.x)*bhi(mv.x);
      dot += blo(kv.y)*blo(mv.y) + bhi(kv.y)*bhi(mv.y);
      dot += blo(kv.z)*blo(mv.z) + bhi(kv.z)*bhi(mv.z);
      dot += blo(kv.w)*blo(mv.w) + bhi(kv.w)*bhi(mv.w);
    }
    float abk2 = params[gb*8+0], C2 = params[gb*8+1], gg2 = params[gb*8+2];
    float l = dot * abk2 * invhn[hh];
    u16 hv = f2bf(__expf(l - C2) * gg2 / Sv[gb]);
    if (hh) hhi[hb] = hv; else hlo[hb] = hv;
  }
  {
    float abk = params[bb*8+0], C = params[bb*8+1], gg = params[bb*8+2];
    float wfac = gg / Sv[bb];
#pragma unroll
    for (int rt = 0; rt < 4; ++rt) {
      int sbase = rt*16 + hi4*4;
      float wv[4];
#pragma unroll
      for (int r = 0; r < 4; ++r) {
        int sl = sbase + r;
        wv[r] = __expf(acc[rt][r] * abk * invmn[sl] - C) * wfac;
      }
      uint2 pkd;
      pkd.x = pk2(wv[0], wv[1]);
      pkd.y = pk2(wv[2], wv[3]);
      *(uint2*)&pool[pb*DMEM + (((sbase >> 2) ^ (pb & 15)) << 2)] = pkd;
    }
  }
  __syncthreads();
  {
    const int g2 = t & 15;
    const int tb = t >> 4;
    const int so = g2 * 4;
#pragma unroll
    for (int p = 0; p < 4; ++p) {
      int pb2 = p*32 + tb;
      int bb2 = bbase + pb2;
      float gg = params[bb2*8+2];
      float c0 = params[bb2*8+3], c1 = params[bb2*8+4], c2 = params[bb2*8+5];
      float og = 1.f - gg;
      const float* pv = prev + (size_t)bb2 * NSLOTS;
      float4 pr = *(const float4*)(pv + s0 + so);
      uint2 wu = *(const uint2*)&pool[pb2*DMEM + ((g2 ^ (pb2 & 15)) << 2)];
      float w0 = blo(wu.x), w1 = bhi(wu.x), w2 = blo(wu.y), w3 = bhi(wu.y);
      float lpr = __shfl_up(pr.w, 1, 64);
      float rpr = __shfl_down(pr.x, 1, 64);
      float lw  = __shfl_up(w3, 1, 64);
      float rw  = __shfl_down(w0, 1, 64);
      if (g2 == 0)  { lpr = pv[(s0 - 1) & NMASK];   lw = bf2f(hlo[pb2]); }
      if (g2 == 15) { rpr = pv[(s0 + SPB) & NMASK]; rw = bf2f(hhi[pb2]); }
      float fm1 = fmaf(og, lpr,  lw);
      float f0  = fmaf(og, pr.x, w0);
      float f1  = fmaf(og, pr.y, w1);
      float f2  = fmaf(og, pr.z, w2);
      float f3  = fmaf(og, pr.w, w3);
      float f4  = fmaf(og, rpr,  rw);
      float4 o;
      o.x = c0*fm1 + c1*f0 + c2*f1;
      o.y = c0*f0  + c1*f1 + c2*f2;
      o.z = c0*f1  + c1*f2 + c2*f3;
      o.w = c0*f2  + c1*f3 + c2*f4;
      *(float4*)(out + (size_t)bb2 * NSLOTS + s0 + so) = o;
    }
  }
}

extern "C" void kernel_launch(void* const* d_in, const int* in_sizes, int n_in,
                              void* d_out, int out_size, void* d_ws, size_t ws_size,
                              hipStream_t stream)
{
  (void)in_sizes; (void)n_in; (void)out_size;
  const float* inp    = (const float*)d_in[0];
  const float* memory = (const float*)d_in[1];
  const float* prev   = (const float*)d_in[2];
  const float* W      = (const float*)d_in[3];
  const float* bias   = (const float*)d_in[4];
  float* out = (float*)d_out;
  char*  ws  = (char*)d_ws;

  u16*   keysbf = (u16*)ws;                    // 32 KB
  float* params = (float*)(ws + 32768);        // 8 KB
  float* Sv     = (float*)(ws + 40960);        // 1 KB
  float* sumpart = (float*)(ws + 49152);       // 1 MB (new) / 2 MB (fb)
  u16*   ug      = (u16*)(ws + 49152 + 1048576); // 67 MB

  const size_t need_new = 49152 + 1048576 + (size_t)NBATCH * NSLOTS * 2u;
  const size_t need_fb  = 49152 + (size_t)NBATCH * NBLK * 4u;

  hipLaunchKernelGGL(ntm_prep, dim3(NBATCH), dim3(128), 0, stream, inp, W, bias, keysbf, params);

  if (ws_size >= need_new) {
    hipLaunchKernelGGL(ntm_dots,   dim3(NBATCH/64, NSLOTS/256), dim3(512), 0, stream,
                       keysbf, memory, params, ug, sumpart);
    hipLaunchKernelGGL(ntm_reduce, dim3(NBATCH), dim3(256), 0, stream, sumpart, Sv, 1024);
    hipLaunchKernelGGL(ntm_conv,   dim3(NSLOTS/2048, NBATCH), dim3(256), 0, stream,
                       ug, params, Sv, prev, out);
  } else {
    float* sp = (ws_size >= need_fb) ? sumpart : out;
    hipLaunchKernelGGL(ntm_stats_fb, dim3(NBLK, 2), dim3(512), 0, stream, keysbf, memory, params, sp);
    hipLaunchKernelGGL(ntm_reduce,   dim3(NBATCH),  dim3(256), 0, stream, sp, Sv, NBLK);
    hipLaunchKernelGGL(ntm_final_fb, dim3(NBLK, 2), dim3(512), 0, stream, keysbf, memory, params, Sv, prev, out);
  }
}

// Round 8
// 120.366 us; speedup vs baseline: 1.1015x; 1.1015x over previous
//
#include <hip/hip_runtime.h>

#define NSLOTS 131072
#define NMASK  (NSLOTS-1)
#define NBATCH 256
#define DMEM   64
#define DIN    256
#define DCOMB  71
#define SPB    64                 // slots per fallback-stats tile
#define NBLK   (NSLOTS/SPB)       // 2048
#define EPSF   1e-8f

typedef unsigned int   u32;
typedef unsigned short u16;
typedef __bf16 bf16x8 __attribute__((ext_vector_type(8)));
typedef float  f32x4  __attribute__((ext_vector_type(4)));

__device__ __forceinline__ u16 f2bf(float f) {
  u32 u = __builtin_bit_cast(u32, f);
  u += 0x7fffu + ((u >> 16) & 1u);          // RNE
  return (u16)(u >> 16);
}
__device__ __forceinline__ float bf2f(u16 v) {
  return __builtin_bit_cast(float, ((u32)v) << 16);
}
__device__ __forceinline__ u32 pk2(float a, float b) {
  return (u32)f2bf(a) | ((u32)f2bf(b) << 16);
}
__device__ __forceinline__ float blo(u32 u){ return __builtin_bit_cast(float, u << 16); }
__device__ __forceinline__ float bhi(u32 u){ return __builtin_bit_cast(float, u & 0xffff0000u); }

// ---------------- kernel 1: combined GEMM + per-batch params ----------------
// params[b*8]: {abk = ks/kn, C = |ks|, gate, ck0, ck1, ck2, -, -}
__global__ __launch_bounds__(128) void ntm_prep(
    const float* __restrict__ inp, const float* __restrict__ W,
    const float* __restrict__ bias, u16* __restrict__ keysbf,
    float* __restrict__ params)
{
  __shared__ float comb[DCOMB];
  const int b = blockIdx.x;
  const int t = threadIdx.x;
  if (t < DCOMB) {
    float acc = bias[t];
    const float* ip = inp + (size_t)b * DIN;
    for (int i = 0; i < DIN; ++i) acc = fmaf(ip[i], W[i*DCOMB + t], acc);
    comb[t] = acc;
  }
  __syncthreads();
  if (t < 64) {
    float k = comb[t];
    keysbf[b*64 + t] = f2bf(k);
    float sq = k * k;
#pragma unroll
    for (int d = 1; d < 64; d <<= 1) sq += __shfl_xor(sq, d, 64);
    if (t == 0) {
      float kn = sqrtf(sq);
      float ks = comb[64];
      params[b*8+0] = ks / kn;                         // abk
      params[b*8+1] = fabsf(ks);                       // softmax shift C (>= max logit)
      params[b*8+2] = 1.f/(1.f + __expf(-comb[65]));   // gate
      float c0 = comb[66], c1 = comb[67], c2 = comb[68];
      float mx = fmaxf(c0, fmaxf(c1, c2));
      float e0 = __expf(c0-mx), e1 = __expf(c1-mx), e2 = __expf(c2-mx);
      float inv = 1.f/(e0+e1+e2);
      params[b*8+3] = e0*inv; params[b*8+4] = e1*inv; params[b*8+5] = e2*inv;
    }
  }
}

// ---------------- kernel A: dots -> u = exp(l - C) (bf16) + partial sums ----------------
// tile: 128 slots x 128 batches. grid (2 batch-halves FAST, 1024 slot tiles).
// memory read total = 2 x 33.5 MB (pair co-dispatched -> second read L3-hit).
__global__ __launch_bounds__(512, 6) void ntm_dots(
    const u16* __restrict__ keysbf, const float* __restrict__ memory,
    const float* __restrict__ params, u16* __restrict__ ug,
    float* __restrict__ sumpart)
{
  __shared__ __align__(16) u16 pool[128*128];       // 32 KB: u bf16, swizzled 8B chunks
  __shared__ __align__(16) u16 meml[128*DMEM];      // 16 KB, swizzled
  __shared__ float invmn[128];
  const int t     = threadIdx.x;
  const int bbase = blockIdx.x * 128;    // batch half (fast axis)
  const int s0    = blockIdx.y * 128;    // slot tile

  { // stage A: 128 memory rows -> bf16 LDS + 1/norm (each thread: 2 rows x 32 B)
    const int r = t >> 3, c8 = t & 7;
#pragma unroll
    for (int h = 0; h < 2; ++h) {
      int rr = r + h*64;
      const float* mp = memory + (size_t)(s0 + rr) * DMEM + c8 * 8;
      float4 f0 = *(const float4*)mp;
      float4 f1 = *(const float4*)(mp + 4);
      uint4 v;
      v.x = pk2(f0.x, f0.y); v.y = pk2(f0.z, f0.w);
      v.z = pk2(f1.x, f1.y); v.w = pk2(f1.z, f1.w);
      *(uint4*)&meml[rr*DMEM + ((c8 ^ (rr & 7)) << 3)] = v;
      float sq = f0.x*f0.x + f0.y*f0.y + f0.z*f0.z + f0.w*f0.w
               + f1.x*f1.x + f1.y*f1.y + f1.z*f1.z + f1.w*f1.w;
      sq += __shfl_xor(sq, 1, 64);
      sq += __shfl_xor(sq, 2, 64);
      sq += __shfl_xor(sq, 4, 64);
      if (c8 == 0) invmn[rr] = rsqrtf(sq);
    }
  }
  __syncthreads();

  const int w = t >> 6, L = t & 63;
  const int li = L & 15, hi4 = L >> 4;
  const int bb = bbase + w*16 + li;
  const int pb = w*16 + li;              // pool row 0..127
  const uint4* kb = (const uint4*)(keysbf + (size_t)bb * DMEM);
  const float abk = params[bb*8+0];
  const float C   = params[bb*8+1];

  f32x4 zero = {0.f, 0.f, 0.f, 0.f};
  f32x4 acc[8];
#pragma unroll
  for (int rt = 0; rt < 8; ++rt) acc[rt] = zero;

#pragma unroll
  for (int ks = 0; ks < 2; ++ks) {
    int cb = ks*4 + hi4;
    bf16x8 bfr = __builtin_bit_cast(bf16x8, kb[cb]);
#pragma unroll
    for (int rt = 0; rt < 8; ++rt) {
      int rr = rt*16 + li;
      bf16x8 af = __builtin_bit_cast(bf16x8, *(const uint4*)&meml[rr*DMEM + ((cb ^ (rr&7)) << 3)]);
      acc[rt] = __builtin_amdgcn_mfma_f32_16x16x32_bf16(af, bfr, acc[rt], 0, 0, 0);
    }
  }

  float s_acc = 0.f;
#pragma unroll
  for (int rt = 0; rt < 8; ++rt) {
    int sbase = rt*16 + hi4*4;           // slot within tile
    float wv[4];
#pragma unroll
    for (int r = 0; r < 4; ++r)
      wv[r] = __expf(acc[rt][r] * abk * invmn[sbase + r] - C);
    s_acc += wv[0] + wv[1] + wv[2] + wv[3];
    uint2 pkd;
    pkd.x = pk2(wv[0], wv[1]);
    pkd.y = pk2(wv[2], wv[3]);
    int chunk = rt*4 + hi4;              // 8B chunk index within row (0..31)
    int cs = chunk ^ (pb & 31);
    *(uint2*)&pool[pb*128 + cs*4] = pkd;
  }
  s_acc += __shfl_xor(s_acc, 16, 64);
  s_acc += __shfl_xor(s_acc, 32, 64);
  if (hi4 == 0) sumpart[(size_t)bb*1024 + blockIdx.y] = s_acc;
  __syncthreads();

  // stage C: write ug coalesced, 8 threads/row x 32 B (256 B runs per row), 2 passes
#pragma unroll
  for (int p = 0; p < 2; ++p) {
    int row = p*64 + (t >> 3);
    int seg = t & 7;
    uint2 wu[4];
#pragma unroll
    for (int j = 0; j < 4; ++j) {
      int c = seg*4 + j;
      int cs = c ^ (row & 31);
      wu[j] = *(const uint2*)&pool[row*128 + cs*4];
    }
    uint4 v0, v1;
    v0.x = wu[0].x; v0.y = wu[0].y; v0.z = wu[1].x; v0.w = wu[1].y;
    v1.x = wu[2].x; v1.y = wu[2].y; v1.z = wu[3].x; v1.w = wu[3].y;
    uint4* dst = (uint4*)(ug + (size_t)(bbase + row) * NSLOTS + s0 + seg*16);
    dst[0] = v0; dst[1] = v1;
  }
}

// ---------------- kernel 3: global S per batch ----------------
__global__ __launch_bounds__(256) void ntm_reduce(
    const float* __restrict__ sumpart, float* __restrict__ Sv, int nparts)
{
  __shared__ float red[4];
  const int b = blockIdx.x, t = threadIdx.x;
  const int w = t >> 6, L = t & 63;
  float s = 0.f;
  for (int i = t; i < nparts; i += 256) s += sumpart[(size_t)b*nparts + i];
#pragma unroll
  for (int d = 1; d < 64; d <<= 1) s += __shfl_xor(s, d, 64);
  if (L == 0) red[w] = s;
  __syncthreads();
  if (t == 0) Sv[b] = red[0] + red[1] + red[2] + red[3];
}

// ---------------- kernel B: streaming gate-blend + 3-tap circular conv, 16 slots/thread ----------------
// grid (32, 256), 256 threads; block covers one batch row x 4096 slots.
__global__ __launch_bounds__(256, 8) void ntm_conv(
    const u16* __restrict__ ug, const float* __restrict__ params,
    const float* __restrict__ Sv, const float* __restrict__ prev,
    float* __restrict__ out)
{
  const int b    = blockIdx.y;
  const int t    = threadIdx.x;
  const int so   = blockIdx.x * 4096 + t * 16;
  const int L    = t & 63;
  const float gg  = params[b*8+2];
  const float c0f = params[b*8+3], c1f = params[b*8+4], c2f = params[b*8+5];
  const float og  = 1.f - gg;
  const float gs  = gg / Sv[b];
  const float* pv = prev + (size_t)b * NSLOTS;
  const u16*   uv = ug   + (size_t)b * NSLOTS;
  float*       ov = out  + (size_t)b * NSLOTS;

  float4 p0 = *(const float4*)(pv + so);
  float4 p1 = *(const float4*)(pv + so + 4);
  float4 p2 = *(const float4*)(pv + so + 8);
  float4 p3 = *(const float4*)(pv + so + 12);
  uint4  u0 = *(const uint4*)(uv + so);        // 8 bf16
  uint4  u1 = *(const uint4*)(uv + so + 8);    // 8 bf16
  float f[16];
  f[0]  = fmaf(og, p0.x, gs * blo(u0.x));
  f[1]  = fmaf(og, p0.y, gs * bhi(u0.x));
  f[2]  = fmaf(og, p0.z, gs * blo(u0.y));
  f[3]  = fmaf(og, p0.w, gs * bhi(u0.y));
  f[4]  = fmaf(og, p1.x, gs * blo(u0.z));
  f[5]  = fmaf(og, p1.y, gs * bhi(u0.z));
  f[6]  = fmaf(og, p1.z, gs * blo(u0.w));
  f[7]  = fmaf(og, p1.w, gs * bhi(u0.w));
  f[8]  = fmaf(og, p2.x, gs * blo(u1.x));
  f[9]  = fmaf(og, p2.y, gs * bhi(u1.x));
  f[10] = fmaf(og, p2.z, gs * blo(u1.y));
  f[11] = fmaf(og, p2.w, gs * bhi(u1.y));
  f[12] = fmaf(og, p3.x, gs * blo(u1.z));
  f[13] = fmaf(og, p3.y, gs * bhi(u1.z));
  f[14] = fmaf(og, p3.z, gs * blo(u1.w));
  f[15] = fmaf(og, p3.w, gs * bhi(u1.w));

  float fl = __shfl_up(f[15], 1, 64);
  float fr = __shfl_down(f[0], 1, 64);
  if (L == 0) {                            // left edge of wave's 1024-slot span
    int sm = (so - 1) & NMASK;
    fl = fmaf(og, pv[sm], gs * bf2f(uv[sm]));
  }
  if (L == 63) {                           // right edge
    int sp = (so + 16) & NMASK;
    fr = fmaf(og, pv[sp], gs * bf2f(uv[sp]));
  }

  float4 o;
  o.x = c0f*fl    + c1f*f[0]  + c2f*f[1];
  o.y = c0f*f[0]  + c1f*f[1]  + c2f*f[2];
  o.z = c0f*f[1]  + c1f*f[2]  + c2f*f[3];
  o.w = c0f*f[2]  + c1f*f[3]  + c2f*f[4];
  *(float4*)(ov + so) = o;
  o.x = c0f*f[3]  + c1f*f[4]  + c2f*f[5];
  o.y = c0f*f[4]  + c1f*f[5]  + c2f*f[6];
  o.z = c0f*f[5]  + c1f*f[6]  + c2f*f[7];
  o.w = c0f*f[6]  + c1f*f[7]  + c2f*f[8];
  *(float4*)(ov + so + 4) = o;
  o.x = c0f*f[7]  + c1f*f[8]  + c2f*f[9];
  o.y = c0f*f[8]  + c1f*f[9]  + c2f*f[10];
  o.z = c0f*f[9]  + c1f*f[10] + c2f*f[11];
  o.w = c0f*f[10] + c1f*f[11] + c2f*f[12];
  *(float4*)(ov + so + 8) = o;
  o.x = c0f*f[11] + c1f*f[12] + c2f*f[13];
  o.y = c0f*f[12] + c1f*f[13] + c2f*f[14];
  o.z = c0f*f[13] + c1f*f[14] + c2f*f[15];
  o.w = c0f*f[14] + c1f*f[15] + c2f*fr;
  *(float4*)(ov + so + 12) = o;
}

// ================= fallback path (ws too small): round-3 validated kernels =================
__global__ __launch_bounds__(512, 8) void ntm_stats_fb(
    const u16* __restrict__ keysbf, const float* __restrict__ memory,
    const float* __restrict__ params, float* __restrict__ sumpart)
{
  __shared__ __align__(16) u16 meml[SPB*DMEM];
  __shared__ float invmn[SPB];
  const int t     = threadIdx.x;
  const int s0    = blockIdx.x * SPB;
  const int bbase = blockIdx.y * 128;
  {
    int r = t >> 3, c8 = t & 7;
    const float* mp = memory + (size_t)(s0 + r) * DMEM + c8 * 8;
    float4 f0 = *(const float4*)mp;
    float4 f1 = *(const float4*)(mp + 4);
    uint4 v;
    v.x = pk2(f0.x, f0.y); v.y = pk2(f0.z, f0.w);
    v.z = pk2(f1.x, f1.y); v.w = pk2(f1.z, f1.w);
    *(uint4*)&meml[r*DMEM + ((c8 ^ (r & 7)) << 3)] = v;
    float sq = f0.x*f0.x + f0.y*f0.y + f0.z*f0.z + f0.w*f0.w
             + f1.x*f1.x + f1.y*f1.y + f1.z*f1.z + f1.w*f1.w;
    sq += __shfl_xor(sq, 1, 64);
    sq += __shfl_xor(sq, 2, 64);
    sq += __shfl_xor(sq, 4, 64);
    if (c8 == 0) invmn[r] = rsqrtf(sq);
  }
  __syncthreads();
  const int w = t >> 6, L = t & 63;
  const int li = L & 15, hi4 = L >> 4;
  const int bb = bbase + w*16 + li;
  const uint4* kb = (const uint4*)(keysbf + (size_t)bb * DMEM);
  f32x4 zero = {0.f, 0.f, 0.f, 0.f};
  f32x4 acc[4];
#pragma unroll
  for (int rt = 0; rt < 4; ++rt) acc[rt] = zero;
#pragma unroll
  for (int ks = 0; ks < 2; ++ks) {
    int cb = ks*4 + hi4;
    bf16x8 bfr = __builtin_bit_cast(bf16x8, kb[cb]);
#pragma unroll
    for (int rt = 0; rt < 4; ++rt) {
      int r = rt*16 + li;
      bf16x8 af = __builtin_bit_cast(bf16x8, *(const uint4*)&meml[r*DMEM + ((cb ^ (r&7)) << 3)]);
      acc[rt] = __builtin_amdgcn_mfma_f32_16x16x32_bf16(af, bfr, acc[rt], 0, 0, 0);
    }
  }
  float abk = params[bb*8 + 0];
  float C   = params[bb*8 + 1];
  float s = 0.f;
#pragma unroll
  for (int rt = 0; rt < 4; ++rt)
#pragma unroll
    for (int r = 0; r < 4; ++r) {
      int sl = rt*16 + hi4*4 + r;
      s += __expf(acc[rt][r] * abk * invmn[sl] - C);
    }
  s += __shfl_xor(s, 16, 64);
  s += __shfl_xor(s, 32, 64);
  if (hi4 == 0) sumpart[(size_t)bb*NBLK + blockIdx.x] = s;
}

__global__ __launch_bounds__(512, 8) void ntm_final_fb(
    const u16* __restrict__ keysbf, const float* __restrict__ memory,
    const float* __restrict__ params, const float* __restrict__ Sv,
    const float* __restrict__ prev, float* __restrict__ out)
{
  __shared__ __align__(16) u16 pool[128*DMEM];
  __shared__ __align__(16) u16 meml[SPB*DMEM];
  __shared__ __align__(16) u16 halom[2*DMEM];
  __shared__ float invmn[SPB];
  __shared__ float invhn[2];
  __shared__ u16 hlo[128], hhi[128];
  const int t     = threadIdx.x;
  const int s0    = blockIdx.x * SPB;
  const int bbase = blockIdx.y * 128;
  {
    int r = t >> 3, c8 = t & 7;
    const float* mp = memory + (size_t)(s0 + r) * DMEM + c8 * 8;
    float4 f0 = *(const float4*)mp;
    float4 f1 = *(const float4*)(mp + 4);
    uint4 v;
    v.x = pk2(f0.x, f0.y); v.y = pk2(f0.z, f0.w);
    v.z = pk2(f1.x, f1.y); v.w = pk2(f1.z, f1.w);
    *(uint4*)&meml[r*DMEM + ((c8 ^ (r & 7)) << 3)] = v;
    float sq = f0.x*f0.x + f0.y*f0.y + f0.z*f0.z + f0.w*f0.w
             + f1.x*f1.x + f1.y*f1.y + f1.z*f1.z + f1.w*f1.w;
    sq += __shfl_xor(sq, 1, 64);
    sq += __shfl_xor(sq, 2, 64);
    sq += __shfl_xor(sq, 4, 64);
    if (c8 == 0) invmn[r] = rsqrtf(sq);
  }
  if (t < 128) {
    int h = t >> 6, m = t & 63;
    int gs = (s0 + (h ? SPB : -1)) & NMASK;
    float v = memory[(size_t)gs * DMEM + m];
    halom[h*DMEM + m] = f2bf(v);
    float sq = v * v;
#pragma unroll
    for (int d = 1; d < 64; d <<= 1) sq += __shfl_xor(sq, d, 64);
    if (m == 0) invhn[h] = rsqrtf(sq);
  }
  __syncthreads();
  const int w = t >> 6, L = t & 63;
  const int li = L & 15, hi4 = L >> 4;
  const int bb = bbase + w*16 + li;
  const int pb = w*16 + li;
  const uint4* kb = (const uint4*)(keysbf + (size_t)bb * DMEM);
  f32x4 zero = {0.f, 0.f, 0.f, 0.f};
  f32x4 acc[4];
#pragma unroll
  for (int rt = 0; rt < 4; ++rt) acc[rt] = zero;
#pragma unroll
  for (int ks = 0; ks < 2; ++ks) {
    int cb = ks*4 + hi4;
    bf16x8 bfr = __builtin_bit_cast(bf16x8, kb[cb]);
#pragma unroll
    for (int rt = 0; rt < 4; ++rt) {
      int r = rt*16 + li;
      bf16x8 af = __builtin_bit_cast(bf16x8, *(const uint4*)&meml[r*DMEM + ((cb ^ (r&7)) << 3)]);
      acc[rt] = __builtin_amdgcn_mfma_f32_16x16x32_bf16(af, bfr, acc[rt], 0, 0, 0);
    }
  }
  if (t < 256) {
    int hb = t & 127, hh = t >> 7;
    int gb = bbase + hb;
    const uint4* kb2 = (const uint4*)(keysbf + (size_t)gb * DMEM);
    float dot = 0.f;
#pragma unroll
    for (int mb = 0; mb < 8; ++mb) {
      uint4 kv = kb2[mb];
      uint4 mv = *(const uint4*)&halom[hh*DMEM + mb*8];
      dot += blo(kv.x)*blo(mv.x) + bhi(kv.x)*bhi(mv.x);
      dot += blo(kv.y)*blo(mv.y) + bhi(kv.y)*bhi(mv.y);
      dot += blo(kv.z)*blo(mv.z) + bhi(kv.z)*bhi(mv.z);
      dot += blo(kv.w)*blo(mv.w) + bhi(kv.w)*bhi(mv.w);
    }
    float abk2 = params[gb*8+0], C2 = params[gb*8+1], gg2 = params[gb*8+2];
    float l = dot * abk2 * invhn[hh];
    u16 hv = f2bf(__expf(l - C2) * gg2 / Sv[gb]);
    if (hh) hhi[hb] = hv; else hlo[hb] = hv;
  }
  {
    float abk = params[bb*8+0], C = params[bb*8+1], gg = params[bb*8+2];
    float wfac = gg / Sv[bb];
#pragma unroll
    for (int rt = 0; rt < 4; ++rt) {
      int sbase = rt*16 + hi4*4;
      float wv[4];
#pragma unroll
      for (int r = 0; r < 4; ++r) {
        int sl = sbase + r;
        wv[r] = __expf(acc[rt][r] * abk * invmn[sl] - C) * wfac;
      }
      uint2 pkd;
      pkd.x = pk2(wv[0], wv[1]);
      pkd.y = pk2(wv[2], wv[3]);
      *(uint2*)&pool[pb*DMEM + (((sbase >> 2) ^ (pb & 15)) << 2)] = pkd;
    }
  }
  __syncthreads();
  {
    const int g2 = t & 15;
    const int tb = t >> 4;
    const int so = g2 * 4;
#pragma unroll
    for (int p = 0; p < 4; ++p) {
      int pb2 = p*32 + tb;
      int bb2 = bbase + pb2;
      float gg = params[bb2*8+2];
      float c0 = params[bb2*8+3], c1 = params[bb2*8+4], c2 = params[bb2*8+5];
      float og = 1.f - gg;
      const float* pv = prev + (size_t)bb2 * NSLOTS;
      float4 pr = *(const float4*)(pv + s0 + so);
      uint2 wu = *(const uint2*)&pool[pb2*DMEM + ((g2 ^ (pb2 & 15)) << 2)];
      float w0 = blo(wu.x), w1 = bhi(wu.x), w2 = blo(wu.y), w3 = bhi(wu.y);
      float lpr = __shfl_up(pr.w, 1, 64);
      float rpr = __shfl_down(pr.x, 1, 64);
      float lw  = __shfl_up(w3, 1, 64);
      float rw  = __shfl_down(w0, 1, 64);
      if (g2 == 0)  { lpr = pv[(s0 - 1) & NMASK];   lw = bf2f(hlo[pb2]); }
      if (g2 == 15) { rpr = pv[(s0 + SPB) & NMASK]; rw = bf2f(hhi[pb2]); }
      float fm1 = fmaf(og, lpr,  lw);
      float f0  = fmaf(og, pr.x, w0);
      float f1  = fmaf(og, pr.y, w1);
      float f2  = fmaf(og, pr.z, w2);
      float f3  = fmaf(og, pr.w, w3);
      float f4  = fmaf(og, rpr,  rw);
      float4 o;
      o.x = c0*fm1 + c1*f0 + c2*f1;
      o.y = c0*f0  + c1*f1 + c2*f2;
      o.z = c0*f1  + c1*f2 + c2*f3;
      o.w = c0*f2  + c1*f3 + c2*f4;
      *(float4*)(out + (size_t)bb2 * NSLOTS + s0 + so) = o;
    }
  }
}

extern "C" void kernel_launch(void* const* d_in, const int* in_sizes, int n_in,
                              void* d_out, int out_size, void* d_ws, size_t ws_size,
                              hipStream_t stream)
{
  (void)in_sizes; (void)n_in; (void)out_size;
  const float* inp    = (const float*)d_in[0];
  const float* memory = (const float*)d_in[1];
  const float* prev   = (const float*)d_in[2];
  const float* W      = (const float*)d_in[3];
  const float* bias   = (const float*)d_in[4];
  float* out = (float*)d_out;
  char*  ws  = (char*)d_ws;

  u16*   keysbf = (u16*)ws;                    // 32 KB
  float* params = (float*)(ws + 32768);        // 8 KB
  float* Sv     = (float*)(ws + 40960);        // 1 KB
  float* sumpart = (float*)(ws + 49152);       // 1 MB (new) / 2 MB (fb)
  u16*   ug      = (u16*)(ws + 49152 + 1048576); // 67 MB

  const size_t need_new = 49152 + 1048576 + (size_t)NBATCH * NSLOTS * 2u;
  const size_t need_fb  = 49152 + (size_t)NBATCH * NBLK * 4u;

  hipLaunchKernelGGL(ntm_prep, dim3(NBATCH), dim3(128), 0, stream, inp, W, bias, keysbf, params);

  if (ws_size >= need_new) {
    hipLaunchKernelGGL(ntm_dots,   dim3(2, NSLOTS/128), dim3(512), 0, stream,
                       keysbf, memory, params, ug, sumpart);
    hipLaunchKernelGGL(ntm_reduce, dim3(NBATCH), dim3(256), 0, stream, sumpart, Sv, 1024);
    hipLaunchKernelGGL(ntm_conv,   dim3(NSLOTS/4096, NBATCH), dim3(256), 0, stream,
                       ug, params, Sv, prev, out);
  } else {
    float* sp = (ws_size >= need_fb) ? sumpart : out;
    hipLaunchKernelGGL(ntm_stats_fb, dim3(NBLK, 2), dim3(512), 0, stream, keysbf, memory, params, sp);
    hipLaunchKernelGGL(ntm_reduce,   dim3(NBATCH),  dim3(256), 0, stream, sp, Sv, NBLK);
    hipLaunchKernelGGL(ntm_final_fb, dim3(NBLK, 2), dim3(512), 0, stream, keysbf, memory, params, Sv, prev, out);
  }
}

// Round 9
// 112.573 us; speedup vs baseline: 1.1777x; 1.0692x over previous
//
#include <hip/hip_runtime.h>

#define NSLOTS 131072
#define NMASK  (NSLOTS-1)
#define NBATCH 256
#define DMEM   64
#define DIN    256
#define DCOMB  71
#define SPB    64                 // slots per fallback-stats tile
#define NBLK   (NSLOTS/SPB)       // 2048
#define EPSF   1e-8f

typedef unsigned int   u32;
typedef unsigned short u16;
typedef __bf16 bf16x8 __attribute__((ext_vector_type(8)));
typedef float  f32x4  __attribute__((ext_vector_type(4)));

__device__ __forceinline__ u16 f2bf(float f) {
  u32 u = __builtin_bit_cast(u32, f);
  u += 0x7fffu + ((u >> 16) & 1u);          // RNE
  return (u16)(u >> 16);
}
__device__ __forceinline__ float bf2f(u16 v) {
  return __builtin_bit_cast(float, ((u32)v) << 16);
}
__device__ __forceinline__ u32 pk2(float a, float b) {
  return (u32)f2bf(a) | ((u32)f2bf(b) << 16);
}
__device__ __forceinline__ float blo(u32 u){ return __builtin_bit_cast(float, u << 16); }
__device__ __forceinline__ float bhi(u32 u){ return __builtin_bit_cast(float, u & 0xffff0000u); }

// ---------------- kernel 1: combined GEMM + per-batch params ----------------
// params[b*8]: {abk = ks/kn, C = |ks|, gate, ck0, ck1, ck2, -, -}
__global__ __launch_bounds__(128) void ntm_prep(
    const float* __restrict__ inp, const float* __restrict__ W,
    const float* __restrict__ bias, u16* __restrict__ keysbf,
    float* __restrict__ params)
{
  __shared__ float comb[DCOMB];
  const int b = blockIdx.x;
  const int t = threadIdx.x;
  if (t < DCOMB) {
    float acc = bias[t];
    const float* ip = inp + (size_t)b * DIN;
    for (int i = 0; i < DIN; ++i) acc = fmaf(ip[i], W[i*DCOMB + t], acc);
    comb[t] = acc;
  }
  __syncthreads();
  if (t < 64) {
    float k = comb[t];
    keysbf[b*64 + t] = f2bf(k);
    float sq = k * k;
#pragma unroll
    for (int d = 1; d < 64; d <<= 1) sq += __shfl_xor(sq, d, 64);
    if (t == 0) {
      float kn = sqrtf(sq);
      float ks = comb[64];
      params[b*8+0] = ks / kn;                         // abk
      params[b*8+1] = fabsf(ks);                       // softmax shift C (>= max logit)
      params[b*8+2] = 1.f/(1.f + __expf(-comb[65]));   // gate
      float c0 = comb[66], c1 = comb[67], c2 = comb[68];
      float mx = fmaxf(c0, fmaxf(c1, c2));
      float e0 = __expf(c0-mx), e1 = __expf(c1-mx), e2 = __expf(c2-mx);
      float inv = 1.f/(e0+e1+e2);
      params[b*8+3] = e0*inv; params[b*8+4] = e1*inv; params[b*8+5] = e2*inv;
    }
  }
}

// ---------------- kernel A: dots -> u = exp(l - C) (bf16) + partial sums ----------------
// tile: 128 slots x 128 batches. grid (2 batch-halves FAST, 1024 slot tiles).
__global__ __launch_bounds__(512, 6) void ntm_dots(
    const u16* __restrict__ keysbf, const float* __restrict__ memory,
    const float* __restrict__ params, u16* __restrict__ ug,
    float* __restrict__ sumpart)
{
  __shared__ __align__(16) u16 pool[128*128];       // 32 KB: u bf16, swizzled 8B chunks
  __shared__ __align__(16) u16 meml[128*DMEM];      // 16 KB, swizzled
  __shared__ float invmn[128];
  const int t     = threadIdx.x;
  const int bbase = blockIdx.x * 128;    // batch half (fast axis)
  const int s0    = blockIdx.y * 128;    // slot tile

  { // stage A: 128 memory rows -> bf16 LDS + 1/norm (each thread: 2 rows x 32 B)
    const int r = t >> 3, c8 = t & 7;
#pragma unroll
    for (int h = 0; h < 2; ++h) {
      int rr = r + h*64;
      const float* mp = memory + (size_t)(s0 + rr) * DMEM + c8 * 8;
      float4 f0 = *(const float4*)mp;
      float4 f1 = *(const float4*)(mp + 4);
      uint4 v;
      v.x = pk2(f0.x, f0.y); v.y = pk2(f0.z, f0.w);
      v.z = pk2(f1.x, f1.y); v.w = pk2(f1.z, f1.w);
      *(uint4*)&meml[rr*DMEM + ((c8 ^ (rr & 7)) << 3)] = v;
      float sq = f0.x*f0.x + f0.y*f0.y + f0.z*f0.z + f0.w*f0.w
               + f1.x*f1.x + f1.y*f1.y + f1.z*f1.z + f1.w*f1.w;
      sq += __shfl_xor(sq, 1, 64);
      sq += __shfl_xor(sq, 2, 64);
      sq += __shfl_xor(sq, 4, 64);
      if (c8 == 0) invmn[rr] = rsqrtf(sq);
    }
  }
  __syncthreads();

  const int w = t >> 6, L = t & 63;
  const int li = L & 15, hi4 = L >> 4;
  const int bb = bbase + w*16 + li;
  const int pb = w*16 + li;              // pool row 0..127
  const uint4* kb = (const uint4*)(keysbf + (size_t)bb * DMEM);
  const float abk = params[bb*8+0];
  const float C   = params[bb*8+1];

  f32x4 zero = {0.f, 0.f, 0.f, 0.f};
  f32x4 acc[8];
#pragma unroll
  for (int rt = 0; rt < 8; ++rt) acc[rt] = zero;

#pragma unroll
  for (int ks = 0; ks < 2; ++ks) {
    int cb = ks*4 + hi4;
    bf16x8 bfr = __builtin_bit_cast(bf16x8, kb[cb]);
#pragma unroll
    for (int rt = 0; rt < 8; ++rt) {
      int rr = rt*16 + li;
      bf16x8 af = __builtin_bit_cast(bf16x8, *(const uint4*)&meml[rr*DMEM + ((cb ^ (rr&7)) << 3)]);
      acc[rt] = __builtin_amdgcn_mfma_f32_16x16x32_bf16(af, bfr, acc[rt], 0, 0, 0);
    }
  }

  float s_acc = 0.f;
#pragma unroll
  for (int rt = 0; rt < 8; ++rt) {
    int sbase = rt*16 + hi4*4;           // slot within tile
    float wv[4];
#pragma unroll
    for (int r = 0; r < 4; ++r)
      wv[r] = __expf(acc[rt][r] * abk * invmn[sbase + r] - C);
    s_acc += wv[0] + wv[1] + wv[2] + wv[3];
    uint2 pkd;
    pkd.x = pk2(wv[0], wv[1]);
    pkd.y = pk2(wv[2], wv[3]);
    int chunk = rt*4 + hi4;              // 8B chunk index within row (0..31)
    int cs = chunk ^ (pb & 31);
    *(uint2*)&pool[pb*128 + cs*4] = pkd;
  }
  s_acc += __shfl_xor(s_acc, 16, 64);
  s_acc += __shfl_xor(s_acc, 32, 64);
  if (hi4 == 0) sumpart[(size_t)bb*1024 + blockIdx.y] = s_acc;
  __syncthreads();

  // stage C: write ug coalesced, 8 threads/row x 32 B (256 B runs per row), 2 passes
#pragma unroll
  for (int p = 0; p < 2; ++p) {
    int row = p*64 + (t >> 3);
    int seg = t & 7;
    uint2 wu[4];
#pragma unroll
    for (int j = 0; j < 4; ++j) {
      int c = seg*4 + j;
      int cs = c ^ (row & 31);
      wu[j] = *(const uint2*)&pool[row*128 + cs*4];
    }
    uint4 v0, v1;
    v0.x = wu[0].x; v0.y = wu[0].y; v0.z = wu[1].x; v0.w = wu[1].y;
    v1.x = wu[2].x; v1.y = wu[2].y; v1.z = wu[3].x; v1.w = wu[3].y;
    uint4* dst = (uint4*)(ug + (size_t)(bbase + row) * NSLOTS + s0 + seg*16);
    dst[0] = v0; dst[1] = v1;
  }
}

// ---------------- kernel 3: global S per batch ----------------
__global__ __launch_bounds__(256) void ntm_reduce(
    const float* __restrict__ sumpart, float* __restrict__ Sv, int nparts)
{
  __shared__ float red[4];
  const int b = blockIdx.x, t = threadIdx.x;
  const int w = t >> 6, L = t & 63;
  float s = 0.f;
  for (int i = t; i < nparts; i += 256) s += sumpart[(size_t)b*nparts + i];
#pragma unroll
  for (int d = 1; d < 64; d <<= 1) s += __shfl_xor(s, d, 64);
  if (L == 0) red[w] = s;
  __syncthreads();
  if (t == 0) Sv[b] = red[0] + red[1] + red[2] + red[3];
}

// ---------------- kernel B: streaming gate-blend + 3-tap circular conv ----------------
// 4 consecutive slots/thread -> every load/store FULLY coalesced (16B/8B lane stride).
// grid (128, 256), 256 threads; block covers one batch row x 1024 slots.
__global__ __launch_bounds__(256, 8) void ntm_conv(
    const u16* __restrict__ ug, const float* __restrict__ params,
    const float* __restrict__ Sv, const float* __restrict__ prev,
    float* __restrict__ out)
{
  const int b    = blockIdx.y;
  const int t    = threadIdx.x;
  const int so   = blockIdx.x * 1024 + t * 4;
  const int L    = t & 63;
  const float gg  = params[b*8+2];
  const float c0f = params[b*8+3], c1f = params[b*8+4], c2f = params[b*8+5];
  const float og  = 1.f - gg;
  const float gs  = gg / Sv[b];
  const float* pv = prev + (size_t)b * NSLOTS;
  const u16*   uv = ug   + (size_t)b * NSLOTS;
  float*       ov = out  + (size_t)b * NSLOTS;

  f32x4 p = __builtin_nontemporal_load((const f32x4*)(pv + so));
  uint2 uu = *(const uint2*)(uv + so);
  float f0 = fmaf(og, p.x, gs * blo(uu.x));
  float f1 = fmaf(og, p.y, gs * bhi(uu.x));
  float f2 = fmaf(og, p.z, gs * blo(uu.y));
  float f3 = fmaf(og, p.w, gs * bhi(uu.y));

  float fl = __shfl_up(f3, 1, 64);
  float fr = __shfl_down(f0, 1, 64);
  if (L == 0) {                            // left edge of wave's 256-slot span
    int sm = (so - 1) & NMASK;
    fl = fmaf(og, pv[sm], gs * bf2f(uv[sm]));
  }
  if (L == 63) {                           // right edge
    int sp = (so + 4) & NMASK;
    fr = fmaf(og, pv[sp], gs * bf2f(uv[sp]));
  }

  f32x4 o;
  o.x = c0f*fl + c1f*f0 + c2f*f1;
  o.y = c0f*f0 + c1f*f1 + c2f*f2;
  o.z = c0f*f1 + c1f*f2 + c2f*f3;
  o.w = c0f*f2 + c1f*f3 + c2f*fr;
  __builtin_nontemporal_store(o, (f32x4*)(ov + so));
}

// ================= fallback path (ws too small): round-3 validated kernels =================
__global__ __launch_bounds__(512, 8) void ntm_stats_fb(
    const u16* __restrict__ keysbf, const float* __restrict__ memory,
    const float* __restrict__ params, float* __restrict__ sumpart)
{
  __shared__ __align__(16) u16 meml[SPB*DMEM];
  __shared__ float invmn[SPB];
  const int t     = threadIdx.x;
  const int s0    = blockIdx.x * SPB;
  const int bbase = blockIdx.y * 128;
  {
    int r = t >> 3, c8 = t & 7;
    const float* mp = memory + (size_t)(s0 + r) * DMEM + c8 * 8;
    float4 f0 = *(const float4*)mp;
    float4 f1 = *(const float4*)(mp + 4);
    uint4 v;
    v.x = pk2(f0.x, f0.y); v.y = pk2(f0.z, f0.w);
    v.z = pk2(f1.x, f1.y); v.w = pk2(f1.z, f1.w);
    *(uint4*)&meml[r*DMEM + ((c8 ^ (r & 7)) << 3)] = v;
    float sq = f0.x*f0.x + f0.y*f0.y + f0.z*f0.z + f0.w*f0.w
             + f1.x*f1.x + f1.y*f1.y + f1.z*f1.z + f1.w*f1.w;
    sq += __shfl_xor(sq, 1, 64);
    sq += __shfl_xor(sq, 2, 64);
    sq += __shfl_xor(sq, 4, 64);
    if (c8 == 0) invmn[r] = rsqrtf(sq);
  }
  __syncthreads();
  const int w = t >> 6, L = t & 63;
  const int li = L & 15, hi4 = L >> 4;
  const int bb = bbase + w*16 + li;
  const uint4* kb = (const uint4*)(keysbf + (size_t)bb * DMEM);
  f32x4 zero = {0.f, 0.f, 0.f, 0.f};
  f32x4 acc[4];
#pragma unroll
  for (int rt = 0; rt < 4; ++rt) acc[rt] = zero;
#pragma unroll
  for (int ks = 0; ks < 2; ++ks) {
    int cb = ks*4 + hi4;
    bf16x8 bfr = __builtin_bit_cast(bf16x8, kb[cb]);
#pragma unroll
    for (int rt = 0; rt < 4; ++rt) {
      int r = rt*16 + li;
      bf16x8 af = __builtin_bit_cast(bf16x8, *(const uint4*)&meml[r*DMEM + ((cb ^ (r&7)) << 3)]);
      acc[rt] = __builtin_amdgcn_mfma_f32_16x16x32_bf16(af, bfr, acc[rt], 0, 0, 0);
    }
  }
  float abk = params[bb*8 + 0];
  float C   = params[bb*8 + 1];
  float s = 0.f;
#pragma unroll
  for (int rt = 0; rt < 4; ++rt)
#pragma unroll
    for (int r = 0; r < 4; ++r) {
      int sl = rt*16 + hi4*4 + r;
      s += __expf(acc[rt][r] * abk * invmn[sl] - C);
    }
  s += __shfl_xor(s, 16, 64);
  s += __shfl_xor(s, 32, 64);
  if (hi4 == 0) sumpart[(size_t)bb*NBLK + blockIdx.x] = s;
}

__global__ __launch_bounds__(512, 8) void ntm_final_fb(
    const u16* __restrict__ keysbf, const float* __restrict__ memory,
    const float* __restrict__ params, const float* __restrict__ Sv,
    const float* __restrict__ prev, float* __restrict__ out)
{
  __shared__ __align__(16) u16 pool[128*DMEM];
  __shared__ __align__(16) u16 meml[SPB*DMEM];
  __shared__ __align__(16) u16 halom[2*DMEM];
  __shared__ float invmn[SPB];
  __shared__ float invhn[2];
  __shared__ u16 hlo[128], hhi[128];
  const int t     = threadIdx.x;
  const int s0    = blockIdx.x * SPB;
  const int bbase = blockIdx.y * 128;
  {
    int r = t >> 3, c8 = t & 7;
    const float* mp = memory + (size_t)(s0 + r) * DMEM + c8 * 8;
    float4 f0 = *(const float4*)mp;
    float4 f1 = *(const float4*)(mp + 4);
    uint4 v;
    v.x = pk2(f0.x, f0.y); v.y = pk2(f0.z, f0.w);
    v.z = pk2(f1.x, f1.y); v.w = pk2(f1.z, f1.w);
    *(uint4*)&meml[r*DMEM + ((c8 ^ (r & 7)) << 3)] = v;
    float sq = f0.x*f0.x + f0.y*f0.y + f0.z*f0.z + f0.w*f0.w
             + f1.x*f1.x + f1.y*f1.y + f1.z*f1.z + f1.w*f1.w;
    sq += __shfl_xor(sq, 1, 64);
    sq += __shfl_xor(sq, 2, 64);
    sq += __shfl_xor(sq, 4, 64);
    if (c8 == 0) invmn[r] = rsqrtf(sq);
  }
  if (t < 128) {
    int h = t >> 6, m = t & 63;
    int gs = (s0 + (h ? SPB : -1)) & NMASK;
    float v = memory[(size_t)gs * DMEM + m];
    halom[h*DMEM + m] = f2bf(v);
    float sq = v * v;
#pragma unroll
    for (int d = 1; d < 64; d <<= 1) sq += __shfl_xor(sq, d, 64);
    if (m == 0) invhn[h] = rsqrtf(sq);
  }
  __syncthreads();
  const int w = t >> 6, L = t & 63;
  const int li = L & 15, hi4 = L >> 4;
  const int bb = bbase + w*16 + li;
  const int pb = w*16 + li;
  const uint4* kb = (const uint4*)(keysbf + (size_t)bb * DMEM);
  f32x4 zero = {0.f, 0.f, 0.f, 0.f};
  f32x4 acc[4];
#pragma unroll
  for (int rt = 0; rt < 4; ++rt) acc[rt] = zero;
#pragma unroll
  for (int ks = 0; ks < 2; ++ks) {
    int cb = ks*4 + hi4;
    bf16x8 bfr = __builtin_bit_cast(bf16x8, kb[cb]);
#pragma unroll
    for (int rt = 0; rt < 4; ++rt) {
      int r = rt*16 + li;
      bf16x8 af = __builtin_bit_cast(bf16x8, *(const uint4*)&meml[r*DMEM + ((cb ^ (r&7)) << 3)]);
      acc[rt] = __builtin_amdgcn_mfma_f32_16x16x32_bf16(af, bfr, acc[rt], 0, 0, 0);
    }
  }
  if (t < 256) {
    int hb = t & 127, hh = t >> 7;
    int gb = bbase + hb;
    const uint4* kb2 = (const uint4*)(keysbf + (size_t)gb * DMEM);
    float dot = 0.f;
#pragma unroll
    for (int mb = 0; mb < 8; ++mb) {
      uint4 kv = kb2[mb];
      uint4 mv = *(const uint4*)&halom[hh*DMEM + mb*8];
      dot += blo(kv.x)*blo(mv.x) + bhi(kv.x)*bhi(mv.x);
      dot += blo(kv.y)*blo(mv.y) + bhi(kv.y)*bhi(mv.y);
      dot += blo(kv.z)*blo(mv.z) + bhi(kv.z)*bhi(mv.z);
      dot += blo(kv.w)*blo(mv.w) + bhi(kv.w)*bhi(mv.w);
    }
    float abk2 = params[gb*8+0], C2 = params[gb*8+1], gg2 = params[gb*8+2];
    float l = dot * abk2 * invhn[hh];
    u16 hv = f2bf(__expf(l - C2) * gg2 / Sv[gb]);
    if (hh) hhi[hb] = hv; else hlo[hb] = hv;
  }
  {
    float abk = params[bb*8+0], C = params[bb*8+1], gg = params[bb*8+2];
    float wfac = gg / Sv[bb];
#pragma unroll
    for (int rt = 0; rt < 4; ++rt) {
      int sbase = rt*16 + hi4*4;
      float wv[4];
#pragma unroll
      for (int r = 0; r < 4; ++r) {
        int sl = sbase + r;
        wv[r] = __expf(acc[rt][r] * abk * invmn[sl] - C) * wfac;
      }
      uint2 pkd;
      pkd.x = pk2(wv[0], wv[1]);
      pkd.y = pk2(wv[2], wv[3]);
      *(uint2*)&pool[pb*DMEM + (((sbase >> 2) ^ (pb & 15)) << 2)] = pkd;
    }
  }
  __syncthreads();
  {
    const int g2 = t & 15;
    const int tb = t >> 4;
    const int so = g2 * 4;
#pragma unroll
    for (int p = 0; p < 4; ++p) {
      int pb2 = p*32 + tb;
      int bb2 = bbase + pb2;
      float gg = params[bb2*8+2];
      float c0 = params[bb2*8+3], c1 = params[bb2*8+4], c2 = params[bb2*8+5];
      float og = 1.f - gg;
      const float* pv = prev + (size_t)bb2 * NSLOTS;
      float4 pr = *(const float4*)(pv + s0 + so);
      uint2 wu = *(const uint2*)&pool[pb2*DMEM + ((g2 ^ (pb2 & 15)) << 2)];
      float w0 = blo(wu.x), w1 = bhi(wu.x), w2 = blo(wu.y), w3 = bhi(wu.y);
      float lpr = __shfl_up(pr.w, 1, 64);
      float rpr = __shfl_down(pr.x, 1, 64);
      float lw  = __shfl_up(w3, 1, 64);
      float rw  = __shfl_down(w0, 1, 64);
      if (g2 == 0)  { lpr = pv[(s0 - 1) & NMASK];   lw = bf2f(hlo[pb2]); }
      if (g2 == 15) { rpr = pv[(s0 + SPB) & NMASK]; rw = bf2f(hhi[pb2]); }
      float fm1 = fmaf(og, lpr,  lw);
      float f0  = fmaf(og, pr.x, w0);
      float f1  = fmaf(og, pr.y, w1);
      float f2  = fmaf(og, pr.z, w2);
      float f3  = fmaf(og, pr.w, w3);
      float f4  = fmaf(og, rpr,  rw);
      float4 o;
      o.x = c0*fm1 + c1*f0 + c2*f1;
      o.y = c0*f0  + c1*f1 + c2*f2;
      o.z = c0*f1  + c1*f2 + c2*f3;
      o.w = c0*f2  + c1*f3 + c2*f4;
      *(float4*)(out + (size_t)bb2 * NSLOTS + s0 + so) = o;
    }
  }
}

extern "C" void kernel_launch(void* const* d_in, const int* in_sizes, int n_in,
                              void* d_out, int out_size, void* d_ws, size_t ws_size,
                              hipStream_t stream)
{
  (void)in_sizes; (void)n_in; (void)out_size;
  const float* inp    = (const float*)d_in[0];
  const float* memory = (const float*)d_in[1];
  const float* prev   = (const float*)d_in[2];
  const float* W      = (const float*)d_in[3];
  const float* bias   = (const float*)d_in[4];
  float* out = (float*)d_out;
  char*  ws  = (char*)d_ws;

  u16*   keysbf = (u16*)ws;                    // 32 KB
  float* params = (float*)(ws + 32768);        // 8 KB
  float* Sv     = (float*)(ws + 40960);        // 1 KB
  float* sumpart = (float*)(ws + 49152);       // 1 MB (new) / 2 MB (fb)
  u16*   ug      = (u16*)(ws + 49152 + 1048576); // 67 MB

  const size_t need_new = 49152 + 1048576 + (size_t)NBATCH * NSLOTS * 2u;
  const size_t need_fb  = 49152 + (size_t)NBATCH * NBLK * 4u;

  hipLaunchKernelGGL(ntm_prep, dim3(NBATCH), dim3(128), 0, stream, inp, W, bias, keysbf, params);

  if (ws_size >= need_new) {
    hipLaunchKernelGGL(ntm_dots,   dim3(2, NSLOTS/128), dim3(512), 0, stream,
                       keysbf, memory, params, ug, sumpart);
    hipLaunchKernelGGL(ntm_reduce, dim3(NBATCH), dim3(256), 0, stream, sumpart, Sv, 1024);
    hipLaunchKernelGGL(ntm_conv,   dim3(NSLOTS/1024, NBATCH), dim3(256), 0, stream,
                       ug, params, Sv, prev, out);
  } else {
    float* sp = (ws_size >= need_fb) ? sumpart : out;
    hipLaunchKernelGGL(ntm_stats_fb, dim3(NBLK, 2), dim3(512), 0, stream, keysbf, memory, params, sp);
    hipLaunchKernelGGL(ntm_reduce,   dim3(NBATCH),  dim3(256), 0, stream, sp, Sv, NBLK);
    hipLaunchKernelGGL(ntm_final_fb, dim3(NBLK, 2), dim3(512), 0, stream, keysbf, memory, params, Sv, prev, out);
  }
}

// Round 10
// 111.216 us; speedup vs baseline: 1.1921x; 1.0122x over previous
//
#include <hip/hip_runtime.h>

#define NSLOTS 131072
#define NMASK  (NSLOTS-1)
#define NBATCH 256
#define DMEM   64
#define DIN    256
#define DCOMB  71
#define SPB    64                 // slots per fallback-stats tile
#define NBLK   (NSLOTS/SPB)       // 2048
#define EPSF   1e-8f

typedef unsigned int   u32;
typedef unsigned short u16;
typedef __bf16 bf16x8 __attribute__((ext_vector_type(8)));
typedef float  f32x4  __attribute__((ext_vector_type(4)));

__device__ __forceinline__ u16 f2bf(float f) {
  u32 u = __builtin_bit_cast(u32, f);
  u += 0x7fffu + ((u >> 16) & 1u);          // RNE
  return (u16)(u >> 16);
}
__device__ __forceinline__ float bf2f(u16 v) {
  return __builtin_bit_cast(float, ((u32)v) << 16);
}
__device__ __forceinline__ u32 pk2(float a, float b) {
  return (u32)f2bf(a) | ((u32)f2bf(b) << 16);
}
__device__ __forceinline__ float blo(u32 u){ return __builtin_bit_cast(float, u << 16); }
__device__ __forceinline__ float bhi(u32 u){ return __builtin_bit_cast(float, u & 0xffff0000u); }

// ---------------- kernel 1: combined GEMM + per-batch params ----------------
// params[b*8]: {abk = ks/kn, C = |ks|, gate, ck0, ck1, ck2, -, -}
__global__ __launch_bounds__(128) void ntm_prep(
    const float* __restrict__ inp, const float* __restrict__ W,
    const float* __restrict__ bias, u16* __restrict__ keysbf,
    float* __restrict__ params)
{
  __shared__ float comb[DCOMB];
  const int b = blockIdx.x;
  const int t = threadIdx.x;
  if (t < DCOMB) {
    float a0 = 0.f, a1 = 0.f, a2 = 0.f, a3 = 0.f;
    const float* ip = inp + (size_t)b * DIN;
#pragma unroll 4
    for (int i = 0; i < DIN; i += 4) {
      a0 = fmaf(ip[i+0], W[(i+0)*DCOMB + t], a0);
      a1 = fmaf(ip[i+1], W[(i+1)*DCOMB + t], a1);
      a2 = fmaf(ip[i+2], W[(i+2)*DCOMB + t], a2);
      a3 = fmaf(ip[i+3], W[(i+3)*DCOMB + t], a3);
    }
    comb[t] = bias[t] + ((a0 + a1) + (a2 + a3));
  }
  __syncthreads();
  if (t < 64) {
    float k = comb[t];
    keysbf[b*64 + t] = f2bf(k);
    float sq = k * k;
#pragma unroll
    for (int d = 1; d < 64; d <<= 1) sq += __shfl_xor(sq, d, 64);
    if (t == 0) {
      float kn = sqrtf(sq);
      float ks = comb[64];
      params[b*8+0] = ks / kn;                         // abk
      params[b*8+1] = fabsf(ks);                       // softmax shift C (>= max logit)
      params[b*8+2] = 1.f/(1.f + __expf(-comb[65]));   // gate
      float c0 = comb[66], c1 = comb[67], c2 = comb[68];
      float mx = fmaxf(c0, fmaxf(c1, c2));
      float e0 = __expf(c0-mx), e1 = __expf(c1-mx), e2 = __expf(c2-mx);
      float inv = 1.f/(e0+e1+e2);
      params[b*8+3] = e0*inv; params[b*8+4] = e1*inv; params[b*8+5] = e2*inv;
    }
  }
}

// ---------------- kernel A: dots -> u = exp(l - C) (bf16, direct global) + partial sums ----------------
// tile: 128 slots x 128 batches. grid (2 batch-halves FAST, 1024 slot tiles).
// No pool: MFMA epilogue writes uint2 (4 consecutive slots) straight to ug;
// L2 write-combining assembles the 32B-per-row pieces into full lines.
__global__ __launch_bounds__(512, 8) void ntm_dots(
    const u16* __restrict__ keysbf, const float* __restrict__ memory,
    const float* __restrict__ params, u16* __restrict__ ug,
    float* __restrict__ sumpart)
{
  __shared__ __align__(16) u16 meml[128*DMEM];      // 16 KB, swizzled
  __shared__ float invmn[128];
  const int t     = threadIdx.x;
  const int bbase = blockIdx.x * 128;    // batch half (fast axis)
  const int s0    = blockIdx.y * 128;    // slot tile

  { // stage: 128 memory rows -> bf16 LDS + 1/norm (each thread: 2 rows x 32 B)
    const int r = t >> 3, c8 = t & 7;
#pragma unroll
    for (int h = 0; h < 2; ++h) {
      int rr = r + h*64;
      const float* mp = memory + (size_t)(s0 + rr) * DMEM + c8 * 8;
      float4 f0 = *(const float4*)mp;
      float4 f1 = *(const float4*)(mp + 4);
      uint4 v;
      v.x = pk2(f0.x, f0.y); v.y = pk2(f0.z, f0.w);
      v.z = pk2(f1.x, f1.y); v.w = pk2(f1.z, f1.w);
      *(uint4*)&meml[rr*DMEM + ((c8 ^ (rr & 7)) << 3)] = v;
      float sq = f0.x*f0.x + f0.y*f0.y + f0.z*f0.z + f0.w*f0.w
               + f1.x*f1.x + f1.y*f1.y + f1.z*f1.z + f1.w*f1.w;
      sq += __shfl_xor(sq, 1, 64);
      sq += __shfl_xor(sq, 2, 64);
      sq += __shfl_xor(sq, 4, 64);
      if (c8 == 0) invmn[rr] = rsqrtf(sq);
    }
  }
  __syncthreads();

  const int w = t >> 6, L = t & 63;
  const int li = L & 15, hi4 = L >> 4;
  const int bb = bbase + w*16 + li;
  const uint4* kb = (const uint4*)(keysbf + (size_t)bb * DMEM);
  const float abk = params[bb*8+0];
  const float C   = params[bb*8+1];
  u16* urow = ug + (size_t)bb * NSLOTS + s0;

  f32x4 zero = {0.f, 0.f, 0.f, 0.f};
  float s_acc = 0.f;

#pragma unroll
  for (int grp = 0; grp < 2; ++grp) {     // 2 groups of 4 row-tiles: caps acc at 16 VGPR
    f32x4 acc[4] = {zero, zero, zero, zero};
#pragma unroll
    for (int ks = 0; ks < 2; ++ks) {
      int cb = ks*4 + hi4;
      bf16x8 bfr = __builtin_bit_cast(bf16x8, kb[cb]);
#pragma unroll
      for (int rt4 = 0; rt4 < 4; ++rt4) {
        int rr = (grp*4 + rt4)*16 + li;
        bf16x8 af = __builtin_bit_cast(bf16x8, *(const uint4*)&meml[rr*DMEM + ((cb ^ (rr&7)) << 3)]);
        acc[rt4] = __builtin_amdgcn_mfma_f32_16x16x32_bf16(af, bfr, acc[rt4], 0, 0, 0);
      }
    }
#pragma unroll
    for (int rt4 = 0; rt4 < 4; ++rt4) {
      int sbase = (grp*4 + rt4)*16 + hi4*4;   // 4 consecutive slots
      float wv[4];
#pragma unroll
      for (int r = 0; r < 4; ++r)
        wv[r] = __expf(acc[rt4][r] * abk * invmn[sbase + r] - C);
      s_acc += (wv[0] + wv[1]) + (wv[2] + wv[3]);
      uint2 pkd;
      pkd.x = pk2(wv[0], wv[1]);
      pkd.y = pk2(wv[2], wv[3]);
      *(uint2*)(urow + sbase) = pkd;
    }
  }
  s_acc += __shfl_xor(s_acc, 16, 64);
  s_acc += __shfl_xor(s_acc, 32, 64);
  if (hi4 == 0) sumpart[(size_t)bb*1024 + blockIdx.y] = s_acc;
}

// ---------------- kernel 3: global S per batch ----------------
__global__ __launch_bounds__(256) void ntm_reduce(
    const float* __restrict__ sumpart, float* __restrict__ Sv, int nparts)
{
  __shared__ float red[4];
  const int b = blockIdx.x, t = threadIdx.x;
  const int w = t >> 6, L = t & 63;
  float s = 0.f;
  for (int i = t; i < nparts; i += 256) s += sumpart[(size_t)b*nparts + i];
#pragma unroll
  for (int d = 1; d < 64; d <<= 1) s += __shfl_xor(s, d, 64);
  if (L == 0) red[w] = s;
  __syncthreads();
  if (t == 0) Sv[b] = red[0] + red[1] + red[2] + red[3];
}

// ---------------- kernel B: streaming gate-blend + 3-tap circular conv ----------------
// 4 consecutive slots/thread -> every load/store FULLY coalesced (16B/8B lane stride).
// grid (128, 256), 256 threads; block covers one batch row x 1024 slots.
__global__ __launch_bounds__(256, 8) void ntm_conv(
    const u16* __restrict__ ug, const float* __restrict__ params,
    const float* __restrict__ Sv, const float* __restrict__ prev,
    float* __restrict__ out)
{
  const int b    = blockIdx.y;
  const int t    = threadIdx.x;
  const int so   = blockIdx.x * 1024 + t * 4;
  const int L    = t & 63;
  const float gg  = params[b*8+2];
  const float c0f = params[b*8+3], c1f = params[b*8+4], c2f = params[b*8+5];
  const float og  = 1.f - gg;
  const float gs  = gg / Sv[b];
  const float* pv = prev + (size_t)b * NSLOTS;
  const u16*   uv = ug   + (size_t)b * NSLOTS;
  float*       ov = out  + (size_t)b * NSLOTS;

  f32x4 p = __builtin_nontemporal_load((const f32x4*)(pv + so));
  uint2 uu = *(const uint2*)(uv + so);
  float f0 = fmaf(og, p.x, gs * blo(uu.x));
  float f1 = fmaf(og, p.y, gs * bhi(uu.x));
  float f2 = fmaf(og, p.z, gs * blo(uu.y));
  float f3 = fmaf(og, p.w, gs * bhi(uu.y));

  float fl = __shfl_up(f3, 1, 64);
  float fr = __shfl_down(f0, 1, 64);
  if (L == 0) {                            // left edge of wave's 256-slot span
    int sm = (so - 1) & NMASK;
    fl = fmaf(og, pv[sm], gs * bf2f(uv[sm]));
  }
  if (L == 63) {                           // right edge
    int sp = (so + 4) & NMASK;
    fr = fmaf(og, pv[sp], gs * bf2f(uv[sp]));
  }

  f32x4 o;
  o.x = c0f*fl + c1f*f0 + c2f*f1;
  o.y = c0f*f0 + c1f*f1 + c2f*f2;
  o.z = c0f*f1 + c1f*f2 + c2f*f3;
  o.w = c0f*f2 + c1f*f3 + c2f*fr;
  __builtin_nontemporal_store(o, (f32x4*)(ov + so));
}

// ================= fallback path (ws too small): round-3 validated kernels =================
__global__ __launch_bounds__(512, 8) void ntm_stats_fb(
    const u16* __restrict__ keysbf, const float* __restrict__ memory,
    const float* __restrict__ params, float* __restrict__ sumpart)
{
  __shared__ __align__(16) u16 meml[SPB*DMEM];
  __shared__ float invmn[SPB];
  const int t     = threadIdx.x;
  const int s0    = blockIdx.x * SPB;
  const int bbase = blockIdx.y * 128;
  {
    int r = t >> 3, c8 = t & 7;
    const float* mp = memory + (size_t)(s0 + r) * DMEM + c8 * 8;
    float4 f0 = *(const float4*)mp;
    float4 f1 = *(const float4*)(mp + 4);
    uint4 v;
    v.x = pk2(f0.x, f0.y); v.y = pk2(f0.z, f0.w);
    v.z = pk2(f1.x, f1.y); v.w = pk2(f1.z, f1.w);
    *(uint4*)&meml[r*DMEM + ((c8 ^ (r & 7)) << 3)] = v;
    float sq = f0.x*f0.x + f0.y*f0.y + f0.z*f0.z + f0.w*f0.w
             + f1.x*f1.x + f1.y*f1.y + f1.z*f1.z + f1.w*f1.w;
    sq += __shfl_xor(sq, 1, 64);
    sq += __shfl_xor(sq, 2, 64);
    sq += __shfl_xor(sq, 4, 64);
    if (c8 == 0) invmn[r] = rsqrtf(sq);
  }
  __syncthreads();
  const int w = t >> 6, L = t & 63;
  const int li = L & 15, hi4 = L >> 4;
  const int bb = bbase + w*16 + li;
  const uint4* kb = (const uint4*)(keysbf + (size_t)bb * DMEM);
  f32x4 zero = {0.f, 0.f, 0.f, 0.f};
  f32x4 acc[4];
#pragma unroll
  for (int rt = 0; rt < 4; ++rt) acc[rt] = zero;
#pragma unroll
  for (int ks = 0; ks < 2; ++ks) {
    int cb = ks*4 + hi4;
    bf16x8 bfr = __builtin_bit_cast(bf16x8, kb[cb]);
#pragma unroll
    for (int rt = 0; rt < 4; ++rt) {
      int r = rt*16 + li;
      bf16x8 af = __builtin_bit_cast(bf16x8, *(const uint4*)&meml[r*DMEM + ((cb ^ (r&7)) << 3)]);
      acc[rt] = __builtin_amdgcn_mfma_f32_16x16x32_bf16(af, bfr, acc[rt], 0, 0, 0);
    }
  }
  float abk = params[bb*8 + 0];
  float C   = params[bb*8 + 1];
  float s = 0.f;
#pragma unroll
  for (int rt = 0; rt < 4; ++rt)
#pragma unroll
    for (int r = 0; r < 4; ++r) {
      int sl = rt*16 + hi4*4 + r;
      s += __expf(acc[rt][r] * abk * invmn[sl] - C);
    }
  s += __shfl_xor(s, 16, 64);
  s += __shfl_xor(s, 32, 64);
  if (hi4 == 0) sumpart[(size_t)bb*NBLK + blockIdx.x] = s;
}

__global__ __launch_bounds__(512, 8) void ntm_final_fb(
    const u16* __restrict__ keysbf, const float* __restrict__ memory,
    const float* __restrict__ params, const float* __restrict__ Sv,
    const float* __restrict__ prev, float* __restrict__ out)
{
  __shared__ __align__(16) u16 pool[128*DMEM];
  __shared__ __align__(16) u16 meml[SPB*DMEM];
  __shared__ __align__(16) u16 halom[2*DMEM];
  __shared__ float invmn[SPB];
  __shared__ float invhn[2];
  __shared__ u16 hlo[128], hhi[128];
  const int t     = threadIdx.x;
  const int s0    = blockIdx.x * SPB;
  const int bbase = blockIdx.y * 128;
  {
    int r = t >> 3, c8 = t & 7;
    const float* mp = memory + (size_t)(s0 + r) * DMEM + c8 * 8;
    float4 f0 = *(const float4*)mp;
    float4 f1 = *(const float4*)(mp + 4);
    uint4 v;
    v.x = pk2(f0.x, f0.y); v.y = pk2(f0.z, f0.w);
    v.z = pk2(f1.x, f1.y); v.w = pk2(f1.z, f1.w);
    *(uint4*)&meml[r*DMEM + ((c8 ^ (r & 7)) << 3)] = v;
    float sq = f0.x*f0.x + f0.y*f0.y + f0.z*f0.z + f0.w*f0.w
             + f1.x*f1.x + f1.y*f1.y + f1.z*f1.z + f1.w*f1.w;
    sq += __shfl_xor(sq, 1, 64);
    sq += __shfl_xor(sq, 2, 64);
    sq += __shfl_xor(sq, 4, 64);
    if (c8 == 0) invmn[r] = rsqrtf(sq);
  }
  if (t < 128) {
    int h = t >> 6, m = t & 63;
    int gs = (s0 + (h ? SPB : -1)) & NMASK;
    float v = memory[(size_t)gs * DMEM + m];
    halom[h*DMEM + m] = f2bf(v);
    float sq = v * v;
#pragma unroll
    for (int d = 1; d < 64; d <<= 1) sq += __shfl_xor(sq, d, 64);
    if (m == 0) invhn[h] = rsqrtf(sq);
  }
  __syncthreads();
  const int w = t >> 6, L = t & 63;
  const int li = L & 15, hi4 = L >> 4;
  const int bb = bbase + w*16 + li;
  const int pb = w*16 + li;
  const uint4* kb = (const uint4*)(keysbf + (size_t)bb * DMEM);
  f32x4 zero = {0.f, 0.f, 0.f, 0.f};
  f32x4 acc[4];
#pragma unroll
  for (int rt = 0; rt < 4; ++rt) acc[rt] = zero;
#pragma unroll
  for (int ks = 0; ks < 2; ++ks) {
    int cb = ks*4 + hi4;
    bf16x8 bfr = __builtin_bit_cast(bf16x8, kb[cb]);
#pragma unroll
    for (int rt = 0; rt < 4; ++rt) {
      int r = rt*16 + li;
      bf16x8 af = __builtin_bit_cast(bf16x8, *(const uint4*)&meml[r*DMEM + ((cb ^ (r&7)) << 3)]);
      acc[rt] = __builtin_amdgcn_mfma_f32_16x16x32_bf16(af, bfr, acc[rt], 0, 0, 0);
    }
  }
  if (t < 256) {
    int hb = t & 127, hh = t >> 7;
    int gb = bbase + hb;
    const uint4* kb2 = (const uint4*)(keysbf + (size_t)gb * DMEM);
    float dot = 0.f;
#pragma unroll
    for (int mb = 0; mb < 8; ++mb) {
      uint4 kv = kb2[mb];
      uint4 mv = *(const uint4*)&halom[hh*DMEM + mb*8];
      dot += blo(kv.x)*blo(mv.x) + bhi(kv.x)*bhi(mv.x);
      dot += blo(kv.y)*blo(mv.y) + bhi(kv.y)*bhi(mv.y);
      dot += blo(kv.z)*blo(mv.z) + bhi(kv.z)*bhi(mv.z);
      dot += blo(kv.w)*blo(mv.w) + bhi(kv.w)*bhi(mv.w);
    }
    float abk2 = params[gb*8+0], C2 = params[gb*8+1], gg2 = params[gb*8+2];
    float l = dot * abk2 * invhn[hh];
    u16 hv = f2bf(__expf(l - C2) * gg2 / Sv[gb]);
    if (hh) hhi[hb] = hv; else hlo[hb] = hv;
  }
  {
    float abk = params[bb*8+0], C = params[bb*8+1], gg = params[bb*8+2];
    float wfac = gg / Sv[bb];
#pragma unroll
    for (int rt = 0; rt < 4; ++rt) {
      int sbase = rt*16 + hi4*4;
      float wv[4];
#pragma unroll
      for (int r = 0; r < 4; ++r) {
        int sl = sbase + r;
        wv[r] = __expf(acc[rt][r] * abk * invmn[sl] - C) * wfac;
      }
      uint2 pkd;
      pkd.x = pk2(wv[0], wv[1]);
      pkd.y = pk2(wv[2], wv[3]);
      *(uint2*)&pool[pb*DMEM + (((sbase >> 2) ^ (pb & 15)) << 2)] = pkd;
    }
  }
  __syncthreads();
  {
    const int g2 = t & 15;
    const int tb = t >> 4;
    const int so = g2 * 4;
#pragma unroll
    for (int p = 0; p < 4; ++p) {
      int pb2 = p*32 + tb;
      int bb2 = bbase + pb2;
      float gg = params[bb2*8+2];
      float c0 = params[bb2*8+3], c1 = params[bb2*8+4], c2 = params[bb2*8+5];
      float og = 1.f - gg;
      const float* pv = prev + (size_t)bb2 * NSLOTS;
      float4 pr = *(const float4*)(pv + s0 + so);
      uint2 wu = *(const uint2*)&pool[pb2*DMEM + ((g2 ^ (pb2 & 15)) << 2)];
      float w0 = blo(wu.x), w1 = bhi(wu.x), w2 = blo(wu.y), w3 = bhi(wu.y);
      float lpr = __shfl_up(pr.w, 1, 64);
      float rpr = __shfl_down(pr.x, 1, 64);
      float lw  = __shfl_up(w3, 1, 64);
      float rw  = __shfl_down(w0, 1, 64);
      if (g2 == 0)  { lpr = pv[(s0 - 1) & NMASK];   lw = bf2f(hlo[pb2]); }
      if (g2 == 15) { rpr = pv[(s0 + SPB) & NMASK]; rw = bf2f(hhi[pb2]); }
      float fm1 = fmaf(og, lpr,  lw);
      float f0  = fmaf(og, pr.x, w0);
      float f1  = fmaf(og, pr.y, w1);
      float f2  = fmaf(og, pr.z, w2);
      float f3  = fmaf(og, pr.w, w3);
      float f4  = fmaf(og, rpr,  rw);
      float4 o;
      o.x = c0*fm1 + c1*f0 + c2*f1;
      o.y = c0*f0  + c1*f1 + c2*f2;
      o.z = c0*f1  + c1*f2 + c2*f3;
      o.w = c0*f2  + c1*f3 + c2*f4;
      *(float4*)(out + (size_t)bb2 * NSLOTS + s0 + so) = o;
    }
  }
}

extern "C" void kernel_launch(void* const* d_in, const int* in_sizes, int n_in,
                              void* d_out, int out_size, void* d_ws, size_t ws_size,
                              hipStream_t stream)
{
  (void)in_sizes; (void)n_in; (void)out_size;
  const float* inp    = (const float*)d_in[0];
  const float* memory = (const float*)d_in[1];
  const float* prev   = (const float*)d_in[2];
  const float* W      = (const float*)d_in[3];
  const float* bias   = (const float*)d_in[4];
  float* out = (float*)d_out;
  char*  ws  = (char*)d_ws;

  u16*   keysbf = (u16*)ws;                    // 32 KB
  float* params = (float*)(ws + 32768);        // 8 KB
  float* Sv     = (float*)(ws + 40960);        // 1 KB
  float* sumpart = (float*)(ws + 49152);       // 1 MB (new) / 2 MB (fb)
  u16*   ug      = (u16*)(ws + 49152 + 1048576); // 67 MB

  const size_t need_new = 49152 + 1048576 + (size_t)NBATCH * NSLOTS * 2u;
  const size_t need_fb  = 49152 + (size_t)NBATCH * NBLK * 4u;

  hipLaunchKernelGGL(ntm_prep, dim3(NBATCH), dim3(128), 0, stream, inp, W, bias, keysbf, params);

  if (ws_size >= need_new) {
    hipLaunchKernelGGL(ntm_dots,   dim3(2, NSLOTS/128), dim3(512), 0, stream,
                       keysbf, memory, params, ug, sumpart);
    hipLaunchKernelGGL(ntm_reduce, dim3(NBATCH), dim3(256), 0, stream, sumpart, Sv, 1024);
    hipLaunchKernelGGL(ntm_conv,   dim3(NSLOTS/1024, NBATCH), dim3(256), 0, stream,
                       ug, params, Sv, prev, out);
  } else {
    float* sp = (ws_size >= need_fb) ? sumpart : out;
    hipLaunchKernelGGL(ntm_stats_fb, dim3(NBLK, 2), dim3(512), 0, stream, keysbf, memory, params, sp);
    hipLaunchKernelGGL(ntm_reduce,   dim3(NBATCH),  dim3(256), 0, stream, sp, Sv, NBLK);
    hipLaunchKernelGGL(ntm_final_fb, dim3(NBLK, 2), dim3(512), 0, stream, keysbf, memory, params, Sv, prev, out);
  }
}

// Round 11
// 96.837 us; speedup vs baseline: 1.3691x; 1.1485x over previous
//
#include <hip/hip_runtime.h>

#define NSLOTS 131072
#define NMASK  (NSLOTS-1)
#define NBATCH 256
#define DMEM   64
#define DIN    256
#define DCOMB  71
#define SPB    64                 // slots per fallback-stats tile
#define NBLK   (NSLOTS/SPB)       // 2048
#define EPSF   1e-8f

typedef unsigned int   u32;
typedef unsigned short u16;
typedef __bf16 bf16x8 __attribute__((ext_vector_type(8)));
typedef float  f32x4  __attribute__((ext_vector_type(4)));

__device__ __forceinline__ u16 f2bf(float f) {
  u32 u = __builtin_bit_cast(u32, f);
  u += 0x7fffu + ((u >> 16) & 1u);          // RNE
  return (u16)(u >> 16);
}
__device__ __forceinline__ float bf2f(u16 v) {
  return __builtin_bit_cast(float, ((u32)v) << 16);
}
__device__ __forceinline__ u32 pk2(float a, float b) {
  return (u32)f2bf(a) | ((u32)f2bf(b) << 16);
}
__device__ __forceinline__ float blo(u32 u){ return __builtin_bit_cast(float, u << 16); }
__device__ __forceinline__ float bhi(u32 u){ return __builtin_bit_cast(float, u & 0xffff0000u); }

// ---------------- kernel 1: combined GEMM + per-batch params ----------------
// params[b*8]: {abk = ks/kn, C = |ks|, gate, ck0, ck1, ck2, -, -}
__global__ __launch_bounds__(128) void ntm_prep(
    const float* __restrict__ inp, const float* __restrict__ W,
    const float* __restrict__ bias, u16* __restrict__ keysbf,
    float* __restrict__ params)
{
  __shared__ float comb[DCOMB];
  const int b = blockIdx.x;
  const int t = threadIdx.x;
  if (t < DCOMB) {
    float a0 = 0.f, a1 = 0.f, a2 = 0.f, a3 = 0.f;
    const float* ip = inp + (size_t)b * DIN;
#pragma unroll 4
    for (int i = 0; i < DIN; i += 4) {
      a0 = fmaf(ip[i+0], W[(i+0)*DCOMB + t], a0);
      a1 = fmaf(ip[i+1], W[(i+1)*DCOMB + t], a1);
      a2 = fmaf(ip[i+2], W[(i+2)*DCOMB + t], a2);
      a3 = fmaf(ip[i+3], W[(i+3)*DCOMB + t], a3);
    }
    comb[t] = bias[t] + ((a0 + a1) + (a2 + a3));
  }
  __syncthreads();
  if (t < 64) {
    float k = comb[t];
    keysbf[b*64 + t] = f2bf(k);
    float sq = k * k;
#pragma unroll
    for (int d = 1; d < 64; d <<= 1) sq += __shfl_xor(sq, d, 64);
    if (t == 0) {
      float kn = sqrtf(sq);
      float ks = comb[64];
      params[b*8+0] = ks / kn;                         // abk
      params[b*8+1] = fabsf(ks);                       // softmax shift C (>= max logit)
      params[b*8+2] = 1.f/(1.f + __expf(-comb[65]));   // gate
      float c0 = comb[66], c1 = comb[67], c2 = comb[68];
      float mx = fmaxf(c0, fmaxf(c1, c2));
      float e0 = __expf(c0-mx), e1 = __expf(c1-mx), e2 = __expf(c2-mx);
      float inv = 1.f/(e0+e1+e2);
      params[b*8+3] = e0*inv; params[b*8+4] = e1*inv; params[b*8+5] = e2*inv;
    }
  }
}

// ---------------- kernel A: dots -> u = exp(l - C) (bf16, direct global) + partial sums ----------------
// tile: 128 slots x 128 batches. grid (2 batch-halves FAST, 1024 slot tiles).
__global__ __launch_bounds__(512, 8) void ntm_dots(
    const u16* __restrict__ keysbf, const float* __restrict__ memory,
    const float* __restrict__ params, u16* __restrict__ ug,
    float* __restrict__ sumpart)
{
  __shared__ __align__(16) u16 meml[128*DMEM];      // 16 KB, swizzled
  __shared__ float invmn[128];
  const int t     = threadIdx.x;
  const int bbase = blockIdx.x * 128;    // batch half (fast axis)
  const int s0    = blockIdx.y * 128;    // slot tile

  { // stage: 128 memory rows -> bf16 LDS + 1/norm (each thread: 2 rows x 32 B)
    const int r = t >> 3, c8 = t & 7;
#pragma unroll
    for (int h = 0; h < 2; ++h) {
      int rr = r + h*64;
      const float* mp = memory + (size_t)(s0 + rr) * DMEM + c8 * 8;
      float4 f0 = *(const float4*)mp;
      float4 f1 = *(const float4*)(mp + 4);
      uint4 v;
      v.x = pk2(f0.x, f0.y); v.y = pk2(f0.z, f0.w);
      v.z = pk2(f1.x, f1.y); v.w = pk2(f1.z, f1.w);
      *(uint4*)&meml[rr*DMEM + ((c8 ^ (rr & 7)) << 3)] = v;
      float sq = f0.x*f0.x + f0.y*f0.y + f0.z*f0.z + f0.w*f0.w
               + f1.x*f1.x + f1.y*f1.y + f1.z*f1.z + f1.w*f1.w;
      sq += __shfl_xor(sq, 1, 64);
      sq += __shfl_xor(sq, 2, 64);
      sq += __shfl_xor(sq, 4, 64);
      if (c8 == 0) invmn[rr] = rsqrtf(sq);
    }
  }
  __syncthreads();

  const int w = t >> 6, L = t & 63;
  const int li = L & 15, hi4 = L >> 4;
  const int bb = bbase + w*16 + li;
  const uint4* kb = (const uint4*)(keysbf + (size_t)bb * DMEM);
  const float abk = params[bb*8+0];
  const float C   = params[bb*8+1];
  u16* urow = ug + (size_t)bb * NSLOTS + s0;

  f32x4 zero = {0.f, 0.f, 0.f, 0.f};
  float s_acc = 0.f;

#pragma unroll
  for (int grp = 0; grp < 2; ++grp) {     // 2 groups of 4 row-tiles: caps acc at 16 VGPR
    f32x4 acc[4] = {zero, zero, zero, zero};
#pragma unroll
    for (int ks = 0; ks < 2; ++ks) {
      int cb = ks*4 + hi4;
      bf16x8 bfr = __builtin_bit_cast(bf16x8, kb[cb]);
#pragma unroll
      for (int rt4 = 0; rt4 < 4; ++rt4) {
        int rr = (grp*4 + rt4)*16 + li;
        bf16x8 af = __builtin_bit_cast(bf16x8, *(const uint4*)&meml[rr*DMEM + ((cb ^ (rr&7)) << 3)]);
        acc[rt4] = __builtin_amdgcn_mfma_f32_16x16x32_bf16(af, bfr, acc[rt4], 0, 0, 0);
      }
    }
#pragma unroll
    for (int rt4 = 0; rt4 < 4; ++rt4) {
      int sbase = (grp*4 + rt4)*16 + hi4*4;   // 4 consecutive slots
      float wv[4];
#pragma unroll
      for (int r = 0; r < 4; ++r)
        wv[r] = __expf(acc[rt4][r] * abk * invmn[sbase + r] - C);
      s_acc += (wv[0] + wv[1]) + (wv[2] + wv[3]);
      uint2 pkd;
      pkd.x = pk2(wv[0], wv[1]);
      pkd.y = pk2(wv[2], wv[3]);
      *(uint2*)(urow + sbase) = pkd;
    }
  }
  s_acc += __shfl_xor(s_acc, 16, 64);
  s_acc += __shfl_xor(s_acc, 32, 64);
  if (hi4 == 0) sumpart[(size_t)bb*1024 + blockIdx.y] = s_acc;
}

// ---------------- kernel 3: global S per batch ----------------
__global__ __launch_bounds__(256) void ntm_reduce(
    const float* __restrict__ sumpart, float* __restrict__ Sv, int nparts)
{
  __shared__ float red[4];
  const int b = blockIdx.x, t = threadIdx.x;
  const int w = t >> 6, L = t & 63;
  float s = 0.f;
  for (int i = t; i < nparts; i += 256) s += sumpart[(size_t)b*nparts + i];
#pragma unroll
  for (int d = 1; d < 64; d <<= 1) s += __shfl_xor(s, d, 64);
  if (L == 0) red[w] = s;
  __syncthreads();
  if (t == 0) Sv[b] = red[0] + red[1] + red[2] + red[3];
}

// ---------------- kernel B: streaming gate-blend + 3-tap circular conv ----------------
// 4 disjoint fully-coalesced 256-slot spans per wave (16 slots/thread, 16B lane stride).
// All 8 main loads in flight before any compute -> 96B/thread MLP.
// grid (32, 256), 256 threads; block covers one batch row x 4096 slots.
__global__ __launch_bounds__(256, 8) void ntm_conv(
    const u16* __restrict__ ug, const float* __restrict__ params,
    const float* __restrict__ Sv, const float* __restrict__ prev,
    float* __restrict__ out)
{
  const int b     = blockIdx.y;
  const int t     = threadIdx.x;
  const int w     = t >> 6, L = t & 63;
  const int wbase = blockIdx.x * 4096 + w * 1024;
  const float gg  = params[b*8+2];
  const float c0f = params[b*8+3], c1f = params[b*8+4], c2f = params[b*8+5];
  const float og  = 1.f - gg;
  const float gs  = gg / Sv[b];
  const float* pv = prev + (size_t)b * NSLOTS;
  const u16*   uv = ug   + (size_t)b * NSLOTS;
  float*       ov = out  + (size_t)b * NSLOTS;

  f32x4 p[4];
  uint2 uu[4];
#pragma unroll
  for (int s = 0; s < 4; ++s) {
    int so = wbase + s*256 + L*4;
    p[s]  = *(const f32x4*)(pv + so);
    uu[s] = *(const uint2*)(uv + so);
  }
  // masked outer-edge loads (independent, issued alongside)
  float lpe = 0.f, lue = 0.f, rpe = 0.f, rue = 0.f;
  if (L == 0)  { int sm = (wbase - 1) & NMASK;    lpe = pv[sm]; lue = bf2f(uv[sm]); }
  if (L == 63) { int sp = (wbase + 1024) & NMASK; rpe = pv[sp]; rue = bf2f(uv[sp]); }

  float f[4][4];
#pragma unroll
  for (int s = 0; s < 4; ++s) {
    f[s][0] = fmaf(og, p[s].x, gs * blo(uu[s].x));
    f[s][1] = fmaf(og, p[s].y, gs * bhi(uu[s].x));
    f[s][2] = fmaf(og, p[s].z, gs * blo(uu[s].y));
    f[s][3] = fmaf(og, p[s].w, gs * bhi(uu[s].y));
  }
  const float fle = fmaf(og, lpe, gs * lue);   // valid on lane 0 only
  const float fre = fmaf(og, rpe, gs * rue);   // valid on lane 63 only

#pragma unroll
  for (int s = 0; s < 4; ++s) {
    // left neighbor of f[s][0]
    float flA = __shfl_up(f[s][3], 1, 64);                       // lane L-1's elem3
    float flB = (s > 0) ? __shfl(f[s-1][3], 63, 64) : 0.f;       // span s-1, lane63 elem3
    float fl  = (L == 0) ? ((s == 0) ? fle : flB) : flA;
    // right neighbor of f[s][3]
    float frA = __shfl_down(f[s][0], 1, 64);                     // lane L+1's elem0
    float frB = (s < 3) ? __shfl(f[s+1][0], 0, 64) : 0.f;        // span s+1, lane0 elem0
    float fr  = (L == 63) ? ((s == 3) ? fre : frB) : frA;

    f32x4 o;
    o.x = c0f*fl      + c1f*f[s][0] + c2f*f[s][1];
    o.y = c0f*f[s][0] + c1f*f[s][1] + c2f*f[s][2];
    o.z = c0f*f[s][1] + c1f*f[s][2] + c2f*f[s][3];
    o.w = c0f*f[s][2] + c1f*f[s][3] + c2f*fr;
    __builtin_nontemporal_store(o, (f32x4*)(ov + wbase + s*256 + L*4));
  }
}

// ================= fallback path (ws too small): round-3 validated kernels =================
__global__ __launch_bounds__(512, 8) void ntm_stats_fb(
    const u16* __restrict__ keysbf, const float* __restrict__ memory,
    const float* __restrict__ params, float* __restrict__ sumpart)
{
  __shared__ __align__(16) u16 meml[SPB*DMEM];
  __shared__ float invmn[SPB];
  const int t     = threadIdx.x;
  const int s0    = blockIdx.x * SPB;
  const int bbase = blockIdx.y * 128;
  {
    int r = t >> 3, c8 = t & 7;
    const float* mp = memory + (size_t)(s0 + r) * DMEM + c8 * 8;
    float4 f0 = *(const float4*)mp;
    float4 f1 = *(const float4*)(mp + 4);
    uint4 v;
    v.x = pk2(f0.x, f0.y); v.y = pk2(f0.z, f0.w);
    v.z = pk2(f1.x, f1.y); v.w = pk2(f1.z, f1.w);
    *(uint4*)&meml[r*DMEM + ((c8 ^ (r & 7)) << 3)] = v;
    float sq = f0.x*f0.x + f0.y*f0.y + f0.z*f0.z + f0.w*f0.w
             + f1.x*f1.x + f1.y*f1.y + f1.z*f1.z + f1.w*f1.w;
    sq += __shfl_xor(sq, 1, 64);
    sq += __shfl_xor(sq, 2, 64);
    sq += __shfl_xor(sq, 4, 64);
    if (c8 == 0) invmn[r] = rsqrtf(sq);
  }
  __syncthreads();
  const int w = t >> 6, L = t & 63;
  const int li = L & 15, hi4 = L >> 4;
  const int bb = bbase + w*16 + li;
  const uint4* kb = (const uint4*)(keysbf + (size_t)bb * DMEM);
  f32x4 zero = {0.f, 0.f, 0.f, 0.f};
  f32x4 acc[4];
#pragma unroll
  for (int rt = 0; rt < 4; ++rt) acc[rt] = zero;
#pragma unroll
  for (int ks = 0; ks < 2; ++ks) {
    int cb = ks*4 + hi4;
    bf16x8 bfr = __builtin_bit_cast(bf16x8, kb[cb]);
#pragma unroll
    for (int rt = 0; rt < 4; ++rt) {
      int r = rt*16 + li;
      bf16x8 af = __builtin_bit_cast(bf16x8, *(const uint4*)&meml[r*DMEM + ((cb ^ (r&7)) << 3)]);
      acc[rt] = __builtin_amdgcn_mfma_f32_16x16x32_bf16(af, bfr, acc[rt], 0, 0, 0);
    }
  }
  float abk = params[bb*8 + 0];
  float C   = params[bb*8 + 1];
  float s = 0.f;
#pragma unroll
  for (int rt = 0; rt < 4; ++rt)
#pragma unroll
    for (int r = 0; r < 4; ++r) {
      int sl = rt*16 + hi4*4 + r;
      s += __expf(acc[rt][r] * abk * invmn[sl] - C);
    }
  s += __shfl_xor(s, 16, 64);
  s += __shfl_xor(s, 32, 64);
  if (hi4 == 0) sumpart[(size_t)bb*NBLK + blockIdx.x] = s;
}

__global__ __launch_bounds__(512, 8) void ntm_final_fb(
    const u16* __restrict__ keysbf, const float* __restrict__ memory,
    const float* __restrict__ params, const float* __restrict__ Sv,
    const float* __restrict__ prev, float* __restrict__ out)
{
  __shared__ __align__(16) u16 pool[128*DMEM];
  __shared__ __align__(16) u16 meml[SPB*DMEM];
  __shared__ __align__(16) u16 halom[2*DMEM];
  __shared__ float invmn[SPB];
  __shared__ float invhn[2];
  __shared__ u16 hlo[128], hhi[128];
  const int t     = threadIdx.x;
  const int s0    = blockIdx.x * SPB;
  const int bbase = blockIdx.y * 128;
  {
    int r = t >> 3, c8 = t & 7;
    const float* mp = memory + (size_t)(s0 + r) * DMEM + c8 * 8;
    float4 f0 = *(const float4*)mp;
    float4 f1 = *(const float4*)(mp + 4);
    uint4 v;
    v.x = pk2(f0.x, f0.y); v.y = pk2(f0.z, f0.w);
    v.z = pk2(f1.x, f1.y); v.w = pk2(f1.z, f1.w);
    *(uint4*)&meml[r*DMEM + ((c8 ^ (r & 7)) << 3)] = v;
    float sq = f0.x*f0.x + f0.y*f0.y + f0.z*f0.z + f0.w*f0.w
             + f1.x*f1.x + f1.y*f1.y + f1.z*f1.z + f1.w*f1.w;
    sq += __shfl_xor(sq, 1, 64);
    sq += __shfl_xor(sq, 2, 64);
    sq += __shfl_xor(sq, 4, 64);
    if (c8 == 0) invmn[r] = rsqrtf(sq);
  }
  if (t < 128) {
    int h = t >> 6, m = t & 63;
    int gs = (s0 + (h ? SPB : -1)) & NMASK;
    float v = memory[(size_t)gs * DMEM + m];
    halom[h*DMEM + m] = f2bf(v);
    float sq = v * v;
#pragma unroll
    for (int d = 1; d < 64; d <<= 1) sq += __shfl_xor(sq, d, 64);
    if (m == 0) invhn[h] = rsqrtf(sq);
  }
  __syncthreads();
  const int w = t >> 6, L = t & 63;
  const int li = L & 15, hi4 = L >> 4;
  const int bb = bbase + w*16 + li;
  const int pb = w*16 + li;
  const uint4* kb = (const uint4*)(keysbf + (size_t)bb * DMEM);
  f32x4 zero = {0.f, 0.f, 0.f, 0.f};
  f32x4 acc[4];
#pragma unroll
  for (int rt = 0; rt < 4; ++rt) acc[rt] = zero;
#pragma unroll
  for (int ks = 0; ks < 2; ++ks) {
    int cb = ks*4 + hi4;
    bf16x8 bfr = __builtin_bit_cast(bf16x8, kb[cb]);
#pragma unroll
    for (int rt = 0; rt < 4; ++rt) {
      int r = rt*16 + li;
      bf16x8 af = __builtin_bit_cast(bf16x8, *(const uint4*)&meml[r*DMEM + ((cb ^ (r&7)) << 3)]);
      acc[rt] = __builtin_amdgcn_mfma_f32_16x16x32_bf16(af, bfr, acc[rt], 0, 0, 0);
    }
  }
  if (t < 256) {
    int hb = t & 127, hh = t >> 7;
    int gb = bbase + hb;
    const uint4* kb2 = (const uint4*)(keysbf + (size_t)gb * DMEM);
    float dot = 0.f;
#pragma unroll
    for (int mb = 0; mb < 8; ++mb) {
      uint4 kv = kb2[mb];
      uint4 mv = *(const uint4*)&halom[hh*DMEM + mb*8];
      dot += blo(kv.x)*blo(mv.x) + bhi(kv.x)*bhi(mv.x);
      dot += blo(kv.y)*blo(mv.y) + bhi(kv.y)*bhi(mv.y);
      dot += blo(kv.z)*blo(mv.z) + bhi(kv.z)*bhi(mv.z);
      dot += blo(kv.w)*blo(mv.w) + bhi(kv.w)*bhi(mv.w);
    }
    float abk2 = params[gb*8+0], C2 = params[gb*8+1], gg2 = params[gb*8+2];
    float l = dot * abk2 * invhn[hh];
    u16 hv = f2bf(__expf(l - C2) * gg2 / Sv[gb]);
    if (hh) hhi[hb] = hv; else hlo[hb] = hv;
  }
  {
    float abk = params[bb*8+0], C = params[bb*8+1], gg = params[bb*8+2];
    float wfac = gg / Sv[bb];
#pragma unroll
    for (int rt = 0; rt < 4; ++rt) {
      int sbase = rt*16 + hi4*4;
      float wv[4];
#pragma unroll
      for (int r = 0; r < 4; ++r) {
        int sl = sbase + r;
        wv[r] = __expf(acc[rt][r] * abk * invmn[sl] - C) * wfac;
      }
      uint2 pkd;
      pkd.x = pk2(wv[0], wv[1]);
      pkd.y = pk2(wv[2], wv[3]);
      *(uint2*)&pool[pb*DMEM + (((sbase >> 2) ^ (pb & 15)) << 2)] = pkd;
    }
  }
  __syncthreads();
  {
    const int g2 = t & 15;
    const int tb = t >> 4;
    const int so = g2 * 4;
#pragma unroll
    for (int p = 0; p < 4; ++p) {
      int pb2 = p*32 + tb;
      int bb2 = bbase + pb2;
      float gg = params[bb2*8+2];
      float c0 = params[bb2*8+3], c1 = params[bb2*8+4], c2 = params[bb2*8+5];
      float og = 1.f - gg;
      const float* pv = prev + (size_t)bb2 * NSLOTS;
      float4 pr = *(const float4*)(pv + s0 + so);
      uint2 wu = *(const uint2*)&pool[pb2*DMEM + ((g2 ^ (pb2 & 15)) << 2)];
      float w0 = blo(wu.x), w1 = bhi(wu.x), w2 = blo(wu.y), w3 = bhi(wu.y);
      float lpr = __shfl_up(pr.w, 1, 64);
      float rpr = __shfl_down(pr.x, 1, 64);
      float lw  = __shfl_up(w3, 1, 64);
      float rw  = __shfl_down(w0, 1, 64);
      if (g2 == 0)  { lpr = pv[(s0 - 1) & NMASK];   lw = bf2f(hlo[pb2]); }
      if (g2 == 15) { rpr = pv[(s0 + SPB) & NMASK]; rw = bf2f(hhi[pb2]); }
      float fm1 = fmaf(og, lpr,  lw);
      float f0  = fmaf(og, pr.x, w0);
      float f1  = fmaf(og, pr.y, w1);
      float f2  = fmaf(og, pr.z, w2);
      float f3  = fmaf(og, pr.w, w3);
      float f4  = fmaf(og, rpr,  rw);
      float4 o;
      o.x = c0*fm1 + c1*f0 + c2*f1;
      o.y = c0*f0  + c1*f1 + c2*f2;
      o.z = c0*f1  + c1*f2 + c2*f3;
      o.w = c0*f2  + c1*f3 + c2*f4;
      *(float4*)(out + (size_t)bb2 * NSLOTS + s0 + so) = o;
    }
  }
}

extern "C" void kernel_launch(void* const* d_in, const int* in_sizes, int n_in,
                              void* d_out, int out_size, void* d_ws, size_t ws_size,
                              hipStream_t stream)
{
  (void)in_sizes; (void)n_in; (void)out_size;
  const float* inp    = (const float*)d_in[0];
  const float* memory = (const float*)d_in[1];
  const float* prev   = (const float*)d_in[2];
  const float* W      = (const float*)d_in[3];
  const float* bias   = (const float*)d_in[4];
  float* out = (float*)d_out;
  char*  ws  = (char*)d_ws;

  u16*   keysbf = (u16*)ws;                    // 32 KB
  float* params = (float*)(ws + 32768);        // 8 KB
  float* Sv     = (float*)(ws + 40960);        // 1 KB
  float* sumpart = (float*)(ws + 49152);       // 1 MB (new) / 2 MB (fb)
  u16*   ug      = (u16*)(ws + 49152 + 1048576); // 67 MB

  const size_t need_new = 49152 + 1048576 + (size_t)NBATCH * NSLOTS * 2u;
  const size_t need_fb  = 49152 + (size_t)NBATCH * NBLK * 4u;

  hipLaunchKernelGGL(ntm_prep, dim3(NBATCH), dim3(128), 0, stream, inp, W, bias, keysbf, params);

  if (ws_size >= need_new) {
    hipLaunchKernelGGL(ntm_dots,   dim3(2, NSLOTS/128), dim3(512), 0, stream,
                       keysbf, memory, params, ug, sumpart);
    hipLaunchKernelGGL(ntm_reduce, dim3(NBATCH), dim3(256), 0, stream, sumpart, Sv, 1024);
    hipLaunchKernelGGL(ntm_conv,   dim3(NSLOTS/4096, NBATCH), dim3(256), 0, stream,
                       ug, params, Sv, prev, out);
  } else {
    float* sp = (ws_size >= need_fb) ? sumpart : out;
    hipLaunchKernelGGL(ntm_stats_fb, dim3(NBLK, 2), dim3(512), 0, stream, keysbf, memory, params, sp);
    hipLaunchKernelGGL(ntm_reduce,   dim3(NBATCH),  dim3(256), 0, stream, sp, Sv, NBLK);
    hipLaunchKernelGGL(ntm_final_fb, dim3(NBLK, 2), dim3(512), 0, stream, keysbf, memory, params, Sv, prev, out);
  }
}